// Round 8
// baseline (155.780 us; speedup 1.0000x reference)
//
#include <hip/hip_runtime.h>

typedef unsigned short u16;
typedef short bf16x8 __attribute__((ext_vector_type(8)));
typedef float f32x4 __attribute__((ext_vector_type(4)));

#define BATCH   16384
#define INDIM   1024
#define KNEUR   1024

__device__ __forceinline__ u16 f2bf(float f) {
  union { float f; unsigned u; } v; v.f = f;
  unsigned r = v.u + 0x7FFFu + ((v.u >> 16) & 1u);   // RNE
  return (u16)(r >> 16);
}
__device__ __forceinline__ float bf2f(u16 h) {
  union { unsigned u; float f; } v; v.u = ((unsigned)h) << 16; return v.f;
}

#define GLDS(gp, lp) __builtin_amdgcn_global_load_lds( \
  (const __attribute__((address_space(1))) void*)(gp), \
  (__attribute__((address_space(3))) void*)(lp), 16, 0, 0)

#define RAWBAR() __builtin_amdgcn_s_barrier()
#define LGKM0() do { asm volatile("s_waitcnt lgkmcnt(0)" ::: "memory"); \
                     __builtin_amdgcn_sched_barrier(0); } while (0)
#define VMC6() asm volatile("s_waitcnt vmcnt(6)" ::: "memory")
#define VMC0() asm volatile("s_waitcnt vmcnt(0)" ::: "memory")

// ============ PREP: x->bf16 + x2 | T table + zero-init | W^T | w2 ============
__global__ __launch_bounds__(256)
void k_prep(const float* __restrict__ x, u16* __restrict__ xb, float* __restrict__ x2,
            const float* __restrict__ w, u16* __restrict__ wt, float* __restrict__ w2,
            const int* __restrict__ loc, const int* __restrict__ itp,
            u16* __restrict__ Tb, float* __restrict__ Tf,
            float* __restrict__ Xf, int* __restrict__ cntcur, float* __restrict__ S) {
  __shared__ float tile[64][65];
  __shared__ float red[4][64];
  int bid = blockIdx.x;
  int t = threadIdx.x;
  if (bid < 4096) {
    int row = bid * 4 + (t >> 6);
    int l = t & 63;
    const float* xr = x + (size_t)row * INDIM;
    u16* xbr = xb + (size_t)row * INDIM;
    float s = 0.f;
    #pragma unroll
    for (int seg = 0; seg < 4; ++seg) {
      float4 v = *(const float4*)(xr + seg * 256 + l * 4);
      ushort4 o; o.x = f2bf(v.x); o.y = f2bf(v.y); o.z = f2bf(v.z); o.w = f2bf(v.w);
      *(ushort4*)(xbr + seg * 256 + l * 4) = o;
      s += v.x * v.x + v.y * v.y + v.z * v.z + v.w * v.w;
    }
    for (int m = 32; m; m >>= 1) s += __shfl_xor(s, m, 64);
    if (l == 0) x2[row] = s;
  } else if (bid < 8192) {
    int id = (bid - 4096) * 256 + t;     // c*1024 + k
    int c = id >> 10, k = id & 1023;
    float corr = 1.f - (float)itp[0] / 100.f;
    float lr = 0.3f * corr;
    float sig = 16.f * corr;
    float inv_s2 = 1.f / (sig * sig);
    int di = loc[2 * c] - loc[2 * k];
    int dj = loc[2 * c + 1] - loc[2 * k + 1];
    float v = lr * __expf(-(float)(di * di + dj * dj) * inv_s2);
    Tf[id] = v;
    Tb[id] = f2bf(v);
    Xf[id] = 0.f;
    if (id < 2304) cntcur[id] = 0;       // cnt[1024] + cursor[1024] + ticket + pad
    if (id < 1024) S[id] = 0.f;
  } else if (bid < 8448) {
    int bb = bid - 8192;
    int bi = bb & 15;
    int bj = bb >> 4;
    int tx = t & 63, ty = t >> 6;
    int i0 = bj * 64, k0 = bi * 64;
    for (int r = ty; r < 64; r += 4)
      tile[r][tx] = w[(size_t)(i0 + r) * KNEUR + k0 + tx];
    __syncthreads();
    for (int r = ty; r < 64; r += 4)
      wt[(size_t)(k0 + r) * INDIM + i0 + tx] = f2bf(tile[tx][r]);
  } else {
    int tx = t & 63, ty = t >> 6;
    int k = (bid - 8448) * 64 + tx;
    float s = 0.f;
    for (int i = ty * 256; i < ty * 256 + 256; ++i) {
      float v = w[(size_t)i * KNEUR + k];
      s += v * v;
    }
    red[ty][tx] = s;
    __syncthreads();
    if (ty == 0) w2[k] = red[0][tx] + red[1][tx] + red[2][tx] + red[3][tx];
  }
}

// ============ GEMM1: 256x256 8-phase MFMA + distance/argmin epilogue =========
__global__ __launch_bounds__(512, 2)
void k_gemm1_8p(const u16* __restrict__ A, const u16* __restrict__ Bm,
                const float* __restrict__ x2, const float* __restrict__ w2,
                float* __restrict__ pmin, int* __restrict__ pidx) {
  __shared__ __align__(16) u16 lds[2][2][2][128 * 64];
  __shared__ float s_rv[2][256];
  __shared__ int   s_ri[2][256];

  int bid = blockIdx.x;
  int swz = (bid & 7) * 32 + (bid >> 3);   // XCD swizzle, 256 blocks
  int mb = swz >> 2, nb = swz & 3;
  int tid = threadIdx.x;
  int lane = tid & 63;
  int wm = (tid >> 6) >> 1, wn = (tid >> 6) & 1;

  const size_t rowA0 = (size_t)mb * 256;
  const size_t rowB0 = (size_t)nb * 256;

  auto STAGE = [&](int u, int op, int qh) {
    if (u >= 16) return;
    const u16* src = (op == 0) ? (A + (rowA0 + qh * 128) * 1024)
                               : (Bm + (rowB0 + qh * 128) * 1024);
    int k0 = u * 64;
    u16* dst0 = &lds[u & 1][op][qh][0];
    #pragma unroll
    for (int j = 0; j < 2; ++j) {
      int s = j * 512 + tid;
      int r = s >> 3;
      int cs = (s & 7) ^ (r & 7);            // inverse-swizzled global source
      GLDS(src + (size_t)r * 1024 + k0 + cs * 8, dst0 + (size_t)s * 8);
    }
  };
  auto LDA = [&](bf16x8 (&a)[2][2], int db, int qm) {
    #pragma unroll
    for (int mt = 0; mt < 2; ++mt)
      #pragma unroll
      for (int kk = 0; kk < 2; ++kk) {
        int row = wm * 32 + mt * 16 + (lane & 15);
        int ch = (kk * 4 + (lane >> 4)) ^ (row & 7);
        a[mt][kk] = *(const bf16x8*)(&lds[db][0][qm][row * 64 + ch * 8]);
      }
  };
  auto LDB = [&](bf16x8 (&b)[4][2], int db, int qn) {
    #pragma unroll
    for (int nt = 0; nt < 4; ++nt)
      #pragma unroll
      for (int kk = 0; kk < 2; ++kk) {
        int row = wn * 64 + nt * 16 + (lane & 15);
        int ch = (kk * 4 + (lane >> 4)) ^ (row & 7);
        b[nt][kk] = *(const bf16x8*)(&lds[db][1][qn][row * 64 + ch * 8]);
      }
  };

  f32x4 acc[2][2][2][4];   // [qm][qn][mt][nt]
  #pragma unroll
  for (int i = 0; i < 2; ++i)
    #pragma unroll
    for (int j = 0; j < 2; ++j)
      #pragma unroll
      for (int m = 0; m < 2; ++m)
        #pragma unroll
        for (int n = 0; n < 4; ++n) {
          acc[i][j][m][n][0] = 0.f; acc[i][j][m][n][1] = 0.f;
          acc[i][j][m][n][2] = 0.f; acc[i][j][m][n][3] = 0.f;
        }

  bf16x8 a[2][2], b0[4][2], b1[4][2];

  #define PHASE(accq, av, bv) do { \
    __builtin_amdgcn_s_setprio(1); \
    _Pragma("unroll") \
    for (int mt = 0; mt < 2; ++mt) \
      _Pragma("unroll") \
      for (int nt = 0; nt < 4; ++nt) \
        _Pragma("unroll") \
        for (int kk = 0; kk < 2; ++kk) \
          accq[mt][nt] = __builtin_amdgcn_mfma_f32_16x16x32_bf16(av[mt][kk], bv[nt][kk], accq[mt][nt], 0, 0, 0); \
    __builtin_amdgcn_s_setprio(0); \
  } while (0)

  // prologue: T0 all 4 halves, then T1 first 3 (order A0,B1,A1,B0)
  STAGE(0, 0, 0); STAGE(0, 1, 1); STAGE(0, 0, 1); STAGE(0, 1, 0);
  STAGE(1, 0, 0); STAGE(1, 1, 1); STAGE(1, 0, 1);
  VMC6();
  RAWBAR();

  #pragma unroll 2
  for (int t = 0; t < 16; ++t) {
    int db = t & 1;
    // P0: quadrant (0,0)
    LDA(a, db, 0); LDB(b0, db, 0);
    STAGE(t + 1, 1, 0);                 // T(t+1).B0
    RAWBAR(); LGKM0();
    PHASE(acc[0][0], a, b0);
    RAWBAR();
    // P1: quadrant (0,1)
    LDB(b1, db, 1);
    STAGE(t + 2, 0, 0);                 // T(t+2).A0
    RAWBAR(); LGKM0();
    PHASE(acc[0][1], a, b1);
    RAWBAR();
    // P2: quadrant (1,1)
    LDA(a, db, 1);
    STAGE(t + 2, 1, 1);                 // T(t+2).B1
    RAWBAR(); LGKM0();
    PHASE(acc[1][1], a, b1);
    RAWBAR();
    // P3: quadrant (1,0)  (b0 reused from registers)
    STAGE(t + 2, 0, 1);                 // T(t+2).A1
    RAWBAR(); LGKM0();
    PHASE(acc[1][0], a, b0);
    if (t < 14) { VMC6(); } else { VMC0(); }
    RAWBAR();
  }

  // epilogue: d2 + min/argmin
  int g = lane >> 4, li = lane & 15;
  #pragma unroll
  for (int qm = 0; qm < 2; ++qm)
    #pragma unroll
    for (int mt = 0; mt < 2; ++mt)
      #pragma unroll
      for (int rr = 0; rr < 4; ++rr) {
        int lrow = qm * 128 + wm * 32 + mt * 16 + g * 4 + rr;
        float xv = x2[rowA0 + lrow];
        float v = 1e30f; int vi = 0x7fffffff;
        #pragma unroll
        for (int qn = 0; qn < 2; ++qn)
          #pragma unroll
          for (int nt = 0; nt < 4; ++nt) {
            int col = (int)rowB0 + qn * 128 + wn * 64 + nt * 16 + li;
            float d2 = xv + w2[col] - 2.f * acc[qm][qn][mt][nt][rr];
            if (d2 < v) { v = d2; vi = col; }
          }
        #pragma unroll
        for (int m = 1; m < 16; m <<= 1) {
          float ov = __shfl_xor(v, m, 64);
          int oi = __shfl_xor(vi, m, 64);
          if (ov < v || (ov == v && oi < vi)) { v = ov; vi = oi; }
        }
        if (li == 0) { s_rv[wn][lrow] = v; s_ri[wn][lrow] = vi; }
      }
  __syncthreads();
  if (tid < 256) {
    float v0 = s_rv[0][tid], v1 = s_rv[1][tid];
    int i0 = s_ri[0][tid], i1 = s_ri[1][tid];
    float v = v0; int vi = i0;
    if (v1 < v0 || (v1 == v0 && i1 < i0)) { v = v1; vi = i1; }
    size_t brow = rowA0 + tid;
    pmin[brow * 4 + nb] = v;
    pidx[brow * 4 + nb] = vi;
  }
  #undef PHASE
}

// ============ GEMM2: split-K=4, atomicAdd acc/B into pre-based outw ==========
__global__ __launch_bounds__(256, 4)
void k_gemm2(const u16* __restrict__ A, const u16* __restrict__ Bm,
             float* __restrict__ outw) {
  __shared__ __align__(16) u16 ldsA[128 * 64];
  __shared__ __align__(16) u16 ldsB[128 * 64];

  int bid = blockIdx.x;
  int ks = bid & 3;
  int tile = bid >> 2;
  int mb = tile >> 3, nb = tile & 7;
  int ktlo = ks * 4, kthi = ktlo + 4;
  int lane = threadIdx.x & 63;
  int wid = threadIdx.x >> 6;
  int wr = wid >> 1, wc = wid & 1;

  f32x4 acc[4][4];
  #pragma unroll
  for (int i = 0; i < 4; ++i)
    #pragma unroll
    for (int j = 0; j < 4; ++j) { acc[i][j][0] = 0.f; acc[i][j][1] = 0.f; acc[i][j][2] = 0.f; acc[i][j][3] = 0.f; }

  const size_t rowA0 = (size_t)mb * 128;
  const size_t rowB0 = (size_t)nb * 128;

  for (int kt = ktlo; kt < kthi; ++kt) {
    int k0 = kt * 64;
    __syncthreads();
    #pragma unroll
    for (int q = 0; q < 4; ++q) {
      int p = q * 256 + wid * 64 + lane;
      int row = p >> 3;
      int clog = (p & 7) ^ (row & 7);
      GLDS(A + (rowA0 + row) * 1024 + k0 + clog * 8,
           ldsA + (size_t)(q * 256 + wid * 64) * 8);
    }
    #pragma unroll
    for (int q = 0; q < 4; ++q) {
      int p = q * 256 + wid * 64 + lane;
      int row = p >> 3;
      int clog = (p & 7) ^ (row & 7);
      GLDS(Bm + (rowB0 + row) * 1024 + k0 + clog * 8,
           ldsB + (size_t)(q * 256 + wid * 64) * 8);
    }
    __syncthreads();
    #pragma unroll
    for (int kk = 0; kk < 2; ++kk) {
      bf16x8 af[4], bfr[4];
      #pragma unroll
      for (int mt = 0; mt < 4; ++mt) {
        int row = wr * 64 + mt * 16 + (lane & 15);
        int ch = (kk * 4 + (lane >> 4)) ^ (row & 7);
        af[mt] = *(const bf16x8*)(ldsA + row * 64 + ch * 8);
      }
      #pragma unroll
      for (int nt = 0; nt < 4; ++nt) {
        int row = wc * 64 + nt * 16 + (lane & 15);
        int ch = (kk * 4 + (lane >> 4)) ^ (row & 7);
        bfr[nt] = *(const bf16x8*)(ldsB + row * 64 + ch * 8);
      }
      #pragma unroll
      for (int mt = 0; mt < 4; ++mt)
        #pragma unroll
        for (int nt = 0; nt < 4; ++nt)
          acc[mt][nt] = __builtin_amdgcn_mfma_f32_16x16x32_bf16(af[mt], bfr[nt], acc[mt][nt], 0, 0, 0);
    }
  }

  const float invB = 1.f / (float)BATCH;
  #pragma unroll
  for (int mt = 0; mt < 4; ++mt)
    #pragma unroll
    for (int nt = 0; nt < 4; ++nt)
      #pragma unroll
      for (int r = 0; r < 4; ++r) {
        int i = (int)rowA0 + wr * 64 + mt * 16 + (lane >> 4) * 4 + r;
        int k = (int)rowB0 + wc * 64 + nt * 16 + (lane & 15);
        atomicAdd(&outw[(size_t)i * KNEUR + k], acc[mt][nt][r] * invB);
      }
}

// ============ BMU + histogram + loss partials + last-block scan/loss ==========
__global__ void k_bmu_scan(const float* __restrict__ pmin, const int* __restrict__ pidx,
                           int* __restrict__ bmu, float* __restrict__ lpart,
                           int* __restrict__ cnt, int* __restrict__ ticket,
                           int* __restrict__ cursor, float* __restrict__ cntf,
                           float* __restrict__ out) {
  int t = threadIdx.x;
  int b = blockIdx.x * 256 + t;
  float v = 1e30f; int vi = 0;
  #pragma unroll
  for (int j = 0; j < 4; ++j) {
    float pv = pmin[(size_t)b * 4 + j];
    if (pv < v) { v = pv; vi = pidx[(size_t)b * 4 + j]; }
  }
  bmu[b] = vi;
  atomicAdd(&cnt[vi], 1);
  float d = sqrtf(fmaxf(v, 0.f));
  __shared__ float red[256];
  red[t] = d;
  __syncthreads();
  for (int s = 128; s > 0; s >>= 1) {
    if (t < s) red[t] += red[t + s];
    __syncthreads();
  }
  if (t == 0) lpart[blockIdx.x] = red[0];

  // last-block ticket: the 64th block to finish does the scan + loss
  __threadfence();
  __shared__ int is_last;
  if (t == 0) is_last = (atomicAdd(ticket, 1) == 63);
  __syncthreads();
  if (!is_last) return;

  __shared__ int sc[256];
  int4 c4 = *(const int4*)(cnt + 4 * t);
  int tsum = c4.x + c4.y + c4.z + c4.w;
  sc[t] = tsum;
  __syncthreads();
  for (int off = 1; off < 256; off <<= 1) {
    int val = sc[t];
    int add = (t >= off) ? sc[t - off] : 0;
    __syncthreads();
    sc[t] = val + add;
    __syncthreads();
  }
  int excl = sc[t] - tsum;
  cursor[4 * t + 0] = excl;
  cursor[4 * t + 1] = excl + c4.x;
  cursor[4 * t + 2] = excl + c4.x + c4.y;
  cursor[4 * t + 3] = excl + c4.x + c4.y + c4.z;
  cntf[4 * t + 0] = (float)c4.x;
  cntf[4 * t + 1] = (float)c4.y;
  cntf[4 * t + 2] = (float)c4.z;
  cntf[4 * t + 3] = (float)c4.w;
  if (t < 64) {
    float l = lpart[t];
    for (int m = 32; m; m >>= 1) l += __shfl_xor(l, m, 64);
    if (t == 0) out[0] = l * (1.f / (float)BATCH);
  }
}

// ============ place (blocks 0..63) + S chunks (blocks 64..127) ============
__global__ void k_place_S(const int* __restrict__ bmu, int* __restrict__ cursor,
                          int* __restrict__ perm,
                          const float* __restrict__ cntf, const float* __restrict__ Tf,
                          float* __restrict__ S) {
  int bid = blockIdx.x;
  int t = threadIdx.x;
  if (bid < 64) {
    int b = bid * 256 + t;
    int c = bmu[b];
    int p = atomicAdd(&cursor[c], 1);
    perm[p] = b;
  } else {
    int chunk = bid - 64;
    int cchunk = chunk >> 2;
    int kb = chunk & 3;
    int k = kb * 256 + t;
    float s = 0.f;
    for (int c = cchunk * 64; c < cchunk * 64 + 64; ++c)
      s += cntf[c] * Tf[(size_t)c * KNEUR + k];
    atomicAdd(&S[k], s);
  }
}

// ============ balanced class-segmented Xsum: Xf[c][i] (f32), 32/block ========
__global__ __launch_bounds__(256)
void k_xsum2(const int* __restrict__ perm, const int* __restrict__ bmu,
             const u16* __restrict__ xb, float* __restrict__ Xf) {
  int t = threadIdx.x;
  int m0 = blockIdx.x * 32;
  int pm[32], cl[32];
  #pragma unroll
  for (int j = 0; j < 32; ++j) pm[j] = perm[m0 + j];
  #pragma unroll
  for (int j = 0; j < 32; ++j) cl[j] = bmu[pm[j]];
  float a0 = 0.f, a1 = 0.f, a2 = 0.f, a3 = 0.f;
  int ccur = cl[0];
  #pragma unroll
  for (int j = 0; j < 32; ++j) {
    if (cl[j] != ccur) {
      float* p = Xf + (size_t)ccur * INDIM + 4 * t;
      atomicAdd(p + 0, a0); atomicAdd(p + 1, a1);
      atomicAdd(p + 2, a2); atomicAdd(p + 3, a3);
      a0 = a1 = a2 = a3 = 0.f;
      ccur = cl[j];
    }
    ushort4 v = *(const ushort4*)(xb + (size_t)pm[j] * INDIM + t * 4);
    a0 += bf2f(v.x); a1 += bf2f(v.y); a2 += bf2f(v.z); a3 += bf2f(v.w);
  }
  float* p = Xf + (size_t)ccur * INDIM + 4 * t;
  atomicAdd(p + 0, a0); atomicAdd(p + 1, a1);
  atomicAdd(p + 2, a2); atomicAdd(p + 3, a3);
}

// ============ Xf->xst transpose (0..255) + outw base write (256..511) ========
__global__ void k_trans_base(const float* __restrict__ Xf, u16* __restrict__ xst,
                             const float* __restrict__ w, const float* __restrict__ S,
                             float* __restrict__ outw) {
  int bid = blockIdx.x;
  int t = threadIdx.x;
  if (bid < 256) {
    __shared__ float tile[64][65];
    int bc = bid & 15;
    int bi = bid >> 4;
    int tx = t & 63, ty = t >> 6;
    int c0 = bc * 64, i0 = bi * 64;
    for (int r = ty; r < 64; r += 4)
      tile[r][tx] = Xf[(size_t)(c0 + r) * INDIM + i0 + tx];
    __syncthreads();
    for (int r = ty; r < 64; r += 4)
      xst[(size_t)(i0 + r) * KNEUR + c0 + tx] = f2bf(tile[tx][r]);
  } else {
    const float invB = 1.f / (float)BATCH;
    size_t base = ((size_t)(bid - 256) * 256 + t) * 16;
    int k = (int)(base & 1023);
    #pragma unroll
    for (int seg = 0; seg < 4; ++seg) {
      float4 wv = *(const float4*)(w + base + seg * 4);
      float4 sv = *(const float4*)(S + k + seg * 4);
      outw[base + seg * 4 + 0] = wv.x - wv.x * sv.x * invB;
      outw[base + seg * 4 + 1] = wv.y - wv.y * sv.y * invB;
      outw[base + seg * 4 + 2] = wv.z - wv.z * sv.z * invB;
      outw[base + seg * 4 + 3] = wv.w - wv.w * sv.w * invB;
    }
  }
}

extern "C" void kernel_launch(void* const* d_in, const int* in_sizes, int n_in,
                              void* d_out, int out_size, void* d_ws, size_t ws_size,
                              hipStream_t stream) {
  const float* x = (const float*)d_in[0];
  const float* w = (const float*)d_in[1];
  const int* loc = (const int*)d_in[2];
  const int* it = (const int*)d_in[3];
  float* out = (float*)d_out;

  char* ws = (char*)d_ws;
  size_t off = 0;
  auto alloc = [&](size_t bytes) -> void* {
    void* p = ws + off;
    off += (bytes + 255) & ~(size_t)255;
    return p;
  };
  u16* xb    = (u16*)  alloc((size_t)BATCH * INDIM * 2);     // 32 MB
  u16* wt    = (u16*)  alloc((size_t)KNEUR * INDIM * 2);
  u16* Tb    = (u16*)  alloc((size_t)KNEUR * KNEUR * 2);
  float* Tf  = (float*)alloc((size_t)KNEUR * KNEUR * 4);
  u16* xst   = (u16*)  alloc((size_t)INDIM * KNEUR * 2);
  float* x2  = (float*)alloc((size_t)BATCH * 4);
  float* w2  = (float*)alloc((size_t)KNEUR * 4);
  float* pmin= (float*)alloc((size_t)BATCH * 4 * 4);
  int* pidx  = (int*)  alloc((size_t)BATCH * 4 * 4);
  int* bmu   = (int*)  alloc((size_t)BATCH * 4);
  float* cntf= (float*)alloc((size_t)KNEUR * 4);
  float* S   = (float*)alloc((size_t)KNEUR * 4);
  float* lpart=(float*)alloc(64 * 4);
  float* Xf  = (float*)alloc((size_t)KNEUR * INDIM * 4);
  int* cntcur= (int*)  alloc((size_t)2304 * 4);   // cnt|cursor|ticket
  int* perm  = (int*)  alloc((size_t)BATCH * 4);
  if (off > ws_size) return;

  int* cnt = cntcur;
  int* cursor = cntcur + KNEUR;
  int* ticket = cntcur + 2 * KNEUR;
  float* outw = out + 1;

  k_prep<<<8464, 256, 0, stream>>>(x, xb, x2, w, wt, w2, loc, it, Tb, Tf, Xf, cntcur, S);
  k_gemm1_8p<<<256, 512, 0, stream>>>(xb, wt, x2, w2, pmin, pidx);
  k_bmu_scan<<<64, 256, 0, stream>>>(pmin, pidx, bmu, lpart, cnt, ticket, cursor, cntf, out);
  k_place_S<<<128, 256, 0, stream>>>(bmu, cursor, perm, cntf, Tf, S);
  k_xsum2<<<BATCH / 32, 256, 0, stream>>>(perm, bmu, xb, Xf);
  k_trans_base<<<512, 256, 0, stream>>>(Xf, xst, w, S, outw);
  k_gemm2<<<256, 256, 0, stream>>>(xst, Tb, outw);
}

// Round 9
// 153.125 us; speedup vs baseline: 1.0173x; 1.0173x over previous
//
#include <hip/hip_runtime.h>

typedef unsigned short u16;
typedef short bf16x8 __attribute__((ext_vector_type(8)));
typedef float f32x4 __attribute__((ext_vector_type(4)));
typedef float f32x16 __attribute__((ext_vector_type(16)));

#define BATCH   16384
#define INDIM   1024
#define KNEUR   1024

__device__ __forceinline__ u16 f2bf(float f) {
  union { float f; unsigned u; } v; v.f = f;
  unsigned r = v.u + 0x7FFFu + ((v.u >> 16) & 1u);   // RNE
  return (u16)(r >> 16);
}
__device__ __forceinline__ float bf2f(u16 h) {
  union { unsigned u; float f; } v; v.u = ((unsigned)h) << 16; return v.f;
}

#define GLDS(gp, lp) __builtin_amdgcn_global_load_lds( \
  (const __attribute__((address_space(1))) void*)(gp), \
  (__attribute__((address_space(3))) void*)(lp), 16, 0, 0)

#define RAWBAR() __builtin_amdgcn_s_barrier()
#define LGKM0() do { asm volatile("s_waitcnt lgkmcnt(0)" ::: "memory"); \
                     __builtin_amdgcn_sched_barrier(0); } while (0)
#define LGKM8() asm volatile("s_waitcnt lgkmcnt(8)" ::: "memory")
#define VMC6() asm volatile("s_waitcnt vmcnt(6)" ::: "memory")
#define VMC0() asm volatile("s_waitcnt vmcnt(0)" ::: "memory")

// ============ PREP: x->bf16 + x2 | T table + zero-init | W^T | w2 ============
__global__ __launch_bounds__(256)
void k_prep(const float* __restrict__ x, u16* __restrict__ xb, float* __restrict__ x2,
            const float* __restrict__ w, u16* __restrict__ wt, float* __restrict__ w2,
            const int* __restrict__ loc, const int* __restrict__ itp,
            u16* __restrict__ Tb, float* __restrict__ Tf,
            float* __restrict__ Xf, int* __restrict__ cntcur, float* __restrict__ S) {
  __shared__ float tile[64][65];
  __shared__ float red[4][64];
  int bid = blockIdx.x;
  int t = threadIdx.x;
  if (bid < 4096) {
    int row = bid * 4 + (t >> 6);
    int l = t & 63;
    const float* xr = x + (size_t)row * INDIM;
    u16* xbr = xb + (size_t)row * INDIM;
    float s = 0.f;
    #pragma unroll
    for (int seg = 0; seg < 4; ++seg) {
      float4 v = *(const float4*)(xr + seg * 256 + l * 4);
      ushort4 o; o.x = f2bf(v.x); o.y = f2bf(v.y); o.z = f2bf(v.z); o.w = f2bf(v.w);
      *(ushort4*)(xbr + seg * 256 + l * 4) = o;
      s += v.x * v.x + v.y * v.y + v.z * v.z + v.w * v.w;
    }
    for (int m = 32; m; m >>= 1) s += __shfl_xor(s, m, 64);
    if (l == 0) x2[row] = s;
  } else if (bid < 8192) {
    int id = (bid - 4096) * 256 + t;     // c*1024 + k
    int c = id >> 10, k = id & 1023;
    float corr = 1.f - (float)itp[0] / 100.f;
    float lr = 0.3f * corr;
    float sig = 16.f * corr;
    float inv_s2 = 1.f / (sig * sig);
    int di = loc[2 * c] - loc[2 * k];
    int dj = loc[2 * c + 1] - loc[2 * k + 1];
    float v = lr * __expf(-(float)(di * di + dj * dj) * inv_s2);
    Tf[id] = v;
    Tb[id] = f2bf(v);
    Xf[id] = 0.f;
    if (id < 2304) cntcur[id] = 0;       // cnt[1024] + cursor[1024] + ticket + pad
    if (id < 1024) S[id] = 0.f;
  } else if (bid < 8448) {
    int bb = bid - 8192;
    int bi = bb & 15;
    int bj = bb >> 4;
    int tx = t & 63, ty = t >> 6;
    int i0 = bj * 64, k0 = bi * 64;
    for (int r = ty; r < 64; r += 4)
      tile[r][tx] = w[(size_t)(i0 + r) * KNEUR + k0 + tx];
    __syncthreads();
    for (int r = ty; r < 64; r += 4)
      wt[(size_t)(k0 + r) * INDIM + i0 + tx] = f2bf(tile[tx][r]);
  } else {
    int tx = t & 63, ty = t >> 6;
    int k = (bid - 8448) * 64 + tx;
    float s = 0.f;
    for (int i = ty * 256; i < ty * 256 + 256; ++i) {
      float v = w[(size_t)i * KNEUR + k];
      s += v * v;
    }
    red[ty][tx] = s;
    __syncthreads();
    if (ty == 0) w2[k] = red[0][tx] + red[1][tx] + red[2][tx] + red[3][tx];
  }
}

// ============ GEMM1: 256x256 8-phase, 32x32x16 MFMA + argmin epilogue ========
// 512 threads = 8 waves (wm 0..3 x wn 0..1). K=1024 -> 16 K-tiles of BK=64.
// LDS: [dbuf][A/B][half][128x64] bf16 = 128 KiB, XOR-swizzled (ch ^= row&7).
// Per phase: 1 A-frag (32 rows) x 2 B-frags (64 cols) x 4 k-steps = 8 MFMA.
// C/D map (m74/m101): col=lane&31, row=(reg&3)+8*(reg>>2)+4*(lane>>5).
__global__ __launch_bounds__(512, 2)
void k_gemm1_8p(const u16* __restrict__ A, const u16* __restrict__ Bm,
                const float* __restrict__ x2, const float* __restrict__ w2,
                float* __restrict__ pmin, int* __restrict__ pidx) {
  __shared__ __align__(16) u16 lds[2][2][2][128 * 64];
  __shared__ float s_rv[2][256];
  __shared__ int   s_ri[2][256];

  int bid = blockIdx.x;
  int swz = (bid & 7) * 32 + (bid >> 3);   // XCD swizzle, 256 blocks
  int mb = swz >> 2, nb = swz & 3;
  int tid = threadIdx.x;
  int lane = tid & 63;
  int wm = (tid >> 6) >> 1, wn = (tid >> 6) & 1;

  const size_t rowA0 = (size_t)mb * 256;
  const size_t rowB0 = (size_t)nb * 256;

  auto STAGE = [&](int u, int op, int qh) {
    if (u >= 16) return;
    const u16* src = (op == 0) ? (A + (rowA0 + qh * 128) * 1024)
                               : (Bm + (rowB0 + qh * 128) * 1024);
    int k0 = u * 64;
    u16* dst0 = &lds[u & 1][op][qh][0];
    #pragma unroll
    for (int j = 0; j < 2; ++j) {
      int s = j * 512 + tid;
      int r = s >> 3;
      int cs = (s & 7) ^ (r & 7);            // inverse-swizzled global source
      GLDS(src + (size_t)r * 1024 + k0 + cs * 8, dst0 + (size_t)s * 8);
    }
  };
  // A-frag: lane holds A[row=wm*32+(lane&31)][k=(lane>>5)*8 + j], per k-step ks
  auto LDA32 = [&](bf16x8 (&a)[4], int db, int qm) {
    int row = wm * 32 + (lane & 31);
    #pragma unroll
    for (int ks = 0; ks < 4; ++ks) {
      int ch = (ks * 2 + (lane >> 5)) ^ (row & 7);
      a[ks] = *(const bf16x8*)(&lds[db][0][qm][row * 64 + ch * 8]);
    }
  };
  auto LDB32 = [&](bf16x8 (&b)[2][4], int db, int qn) {
    #pragma unroll
    for (int nf = 0; nf < 2; ++nf) {
      int row = wn * 64 + nf * 32 + (lane & 31);
      #pragma unroll
      for (int ks = 0; ks < 4; ++ks) {
        int ch = (ks * 2 + (lane >> 5)) ^ (row & 7);
        b[nf][ks] = *(const bf16x8*)(&lds[db][1][qn][row * 64 + ch * 8]);
      }
    }
  };

  f32x16 acc[2][2][2];   // [qm][qn][nf]
  #pragma unroll
  for (int i = 0; i < 2; ++i)
    #pragma unroll
    for (int j = 0; j < 2; ++j)
      #pragma unroll
      for (int n = 0; n < 2; ++n)
        #pragma unroll
        for (int e = 0; e < 16; ++e) acc[i][j][n][e] = 0.f;

  bf16x8 a[4], b0[2][4], b1[2][4];

  #define PHASE32(accq, av, bv) do { \
    __builtin_amdgcn_s_setprio(1); \
    _Pragma("unroll") \
    for (int nf = 0; nf < 2; ++nf) \
      _Pragma("unroll") \
      for (int ks = 0; ks < 4; ++ks) \
        accq[nf] = __builtin_amdgcn_mfma_f32_32x32x16_bf16(av[ks], bv[nf][ks], accq[nf], 0, 0, 0); \
    __builtin_amdgcn_s_setprio(0); \
  } while (0)

  // prologue: T0 all 4 halves, then T1 first 3 (order A0,B1,A1,B0)
  STAGE(0, 0, 0); STAGE(0, 1, 1); STAGE(0, 0, 1); STAGE(0, 1, 0);
  STAGE(1, 0, 0); STAGE(1, 1, 1); STAGE(1, 0, 1);
  VMC6();
  RAWBAR();

  for (int t = 0; t < 16; ++t) {
    int db = t & 1;
    // P0: quadrant (0,0) — 12 ds_reads
    LDA32(a, db, 0); LDB32(b0, db, 0);
    STAGE(t + 1, 1, 0);                 // T(t+1).B0
    LGKM8();
    RAWBAR(); LGKM0();
    PHASE32(acc[0][0], a, b0);
    RAWBAR();
    // P1: quadrant (0,1)
    LDB32(b1, db, 1);
    STAGE(t + 2, 0, 0);                 // T(t+2).A0
    RAWBAR(); LGKM0();
    PHASE32(acc[0][1], a, b1);
    RAWBAR();
    // P2: quadrant (1,1)
    LDA32(a, db, 1);
    STAGE(t + 2, 1, 1);                 // T(t+2).B1
    RAWBAR(); LGKM0();
    PHASE32(acc[1][1], a, b1);
    RAWBAR();
    // P3: quadrant (1,0)  (b0 reused from registers)
    STAGE(t + 2, 0, 1);                 // T(t+2).A1
    RAWBAR(); LGKM0();
    PHASE32(acc[1][0], a, b0);
    if (t < 14) { VMC6(); } else { VMC0(); }
    RAWBAR();
  }

  // epilogue: d2 + min/argmin (32x32 C/D layout)
  int h = lane >> 5, cl = lane & 31;
  #pragma unroll
  for (int qm = 0; qm < 2; ++qm)
    #pragma unroll
    for (int reg = 0; reg < 16; ++reg) {
      int lrow = qm * 128 + wm * 32 + (reg & 3) + 8 * (reg >> 2) + 4 * h;
      float xv = x2[rowA0 + lrow];
      float v = 1e30f; int vi = 0x7fffffff;
      #pragma unroll
      for (int qn = 0; qn < 2; ++qn)
        #pragma unroll
        for (int nf = 0; nf < 2; ++nf) {
          int col = (int)rowB0 + qn * 128 + wn * 64 + nf * 32 + cl;
          float d2 = xv + w2[col] - 2.f * acc[qm][qn][nf][reg];
          if (d2 < v) { v = d2; vi = col; }   // cols ascending -> first-min kept
        }
      #pragma unroll
      for (int m = 1; m < 32; m <<= 1) {
        float ov = __shfl_xor(v, m, 64);
        int oi = __shfl_xor(vi, m, 64);
        if (ov < v || (ov == v && oi < vi)) { v = ov; vi = oi; }
      }
      if (cl == 0) { s_rv[wn][lrow] = v; s_ri[wn][lrow] = vi; }
    }
  __syncthreads();
  if (tid < 256) {
    float v0 = s_rv[0][tid], v1 = s_rv[1][tid];
    int i0 = s_ri[0][tid], i1 = s_ri[1][tid];
    float v = v0; int vi = i0;
    if (v1 < v0 || (v1 == v0 && i1 < i0)) { v = v1; vi = i1; }
    size_t brow = rowA0 + tid;
    pmin[brow * 4 + nb] = v;
    pidx[brow * 4 + nb] = vi;
  }
  #undef PHASE32
}

// ============ GEMM2 (m97 128^2 structure), split-K=4 partials into P4 ========
__global__ __launch_bounds__(256, 4)
void k_gemm2(const u16* __restrict__ A, const u16* __restrict__ Bm,
             float* __restrict__ P4) {
  __shared__ __align__(16) u16 ldsA[128 * 64];
  __shared__ __align__(16) u16 ldsB[128 * 64];

  int bid = blockIdx.x;
  int ks = bid & 3;
  int tile = bid >> 2;
  int mb = tile >> 3, nb = tile & 7;
  int ktlo = ks * 4, kthi = ktlo + 4;
  int lane = threadIdx.x & 63;
  int wid = threadIdx.x >> 6;
  int wr = wid >> 1, wc = wid & 1;

  f32x4 acc[4][4];
  #pragma unroll
  for (int i = 0; i < 4; ++i)
    #pragma unroll
    for (int j = 0; j < 4; ++j) { acc[i][j][0] = 0.f; acc[i][j][1] = 0.f; acc[i][j][2] = 0.f; acc[i][j][3] = 0.f; }

  const size_t rowA0 = (size_t)mb * 128;
  const size_t rowB0 = (size_t)nb * 128;

  for (int kt = ktlo; kt < kthi; ++kt) {
    int k0 = kt * 64;
    __syncthreads();
    #pragma unroll
    for (int q = 0; q < 4; ++q) {
      int p = q * 256 + wid * 64 + lane;
      int row = p >> 3;
      int clog = (p & 7) ^ (row & 7);
      GLDS(A + (rowA0 + row) * 1024 + k0 + clog * 8,
           ldsA + (size_t)(q * 256 + wid * 64) * 8);
    }
    #pragma unroll
    for (int q = 0; q < 4; ++q) {
      int p = q * 256 + wid * 64 + lane;
      int row = p >> 3;
      int clog = (p & 7) ^ (row & 7);
      GLDS(Bm + (rowB0 + row) * 1024 + k0 + clog * 8,
           ldsB + (size_t)(q * 256 + wid * 64) * 8);
    }
    __syncthreads();
    #pragma unroll
    for (int kk = 0; kk < 2; ++kk) {
      bf16x8 af[4], bfr[4];
      #pragma unroll
      for (int mt = 0; mt < 4; ++mt) {
        int row = wr * 64 + mt * 16 + (lane & 15);
        int ch = (kk * 4 + (lane >> 4)) ^ (row & 7);
        af[mt] = *(const bf16x8*)(ldsA + row * 64 + ch * 8);
      }
      #pragma unroll
      for (int nt = 0; nt < 4; ++nt) {
        int row = wc * 64 + nt * 16 + (lane & 15);
        int ch = (kk * 4 + (lane >> 4)) ^ (row & 7);
        bfr[nt] = *(const bf16x8*)(ldsB + row * 64 + ch * 8);
      }
      #pragma unroll
      for (int mt = 0; mt < 4; ++mt)
        #pragma unroll
        for (int nt = 0; nt < 4; ++nt)
          acc[mt][nt] = __builtin_amdgcn_mfma_f32_16x16x32_bf16(af[mt], bfr[nt], acc[mt][nt], 0, 0, 0);
    }
  }

  float* base = P4 + ((size_t)ks << 20);
  #pragma unroll
  for (int mt = 0; mt < 4; ++mt)
    #pragma unroll
    for (int nt = 0; nt < 4; ++nt)
      #pragma unroll
      for (int r = 0; r < 4; ++r) {
        int i = (int)rowA0 + wr * 64 + mt * 16 + (lane >> 4) * 4 + r;
        int k = (int)rowB0 + wc * 64 + nt * 16 + (lane & 15);
        base[(size_t)i * KNEUR + k] = acc[mt][nt][r];
      }
}

// ============ BMU + histogram + loss partials + last-block scan/loss ==========
__global__ void k_bmu_scan(const float* __restrict__ pmin, const int* __restrict__ pidx,
                           int* __restrict__ bmu, float* __restrict__ lpart,
                           int* __restrict__ cnt, int* __restrict__ ticket,
                           int* __restrict__ cursor, float* __restrict__ cntf,
                           float* __restrict__ out) {
  int t = threadIdx.x;
  int b = blockIdx.x * 256 + t;
  float v = 1e30f; int vi = 0;
  #pragma unroll
  for (int j = 0; j < 4; ++j) {
    float pv = pmin[(size_t)b * 4 + j];
    if (pv < v) { v = pv; vi = pidx[(size_t)b * 4 + j]; }
  }
  bmu[b] = vi;
  atomicAdd(&cnt[vi], 1);
  float d = sqrtf(fmaxf(v, 0.f));
  __shared__ float red[256];
  red[t] = d;
  __syncthreads();
  for (int s = 128; s > 0; s >>= 1) {
    if (t < s) red[t] += red[t + s];
    __syncthreads();
  }
  if (t == 0) lpart[blockIdx.x] = red[0];

  // last-block ticket: the 64th block to finish does the scan + loss
  __threadfence();
  __shared__ int is_last;
  if (t == 0) is_last = (atomicAdd(ticket, 1) == 63);
  __syncthreads();
  if (!is_last) return;

  __shared__ int sc[256];
  int4 c4 = *(const int4*)(cnt + 4 * t);
  int tsum = c4.x + c4.y + c4.z + c4.w;
  sc[t] = tsum;
  __syncthreads();
  for (int off = 1; off < 256; off <<= 1) {
    int val = sc[t];
    int add = (t >= off) ? sc[t - off] : 0;
    __syncthreads();
    sc[t] = val + add;
    __syncthreads();
  }
  int excl = sc[t] - tsum;
  cursor[4 * t + 0] = excl;
  cursor[4 * t + 1] = excl + c4.x;
  cursor[4 * t + 2] = excl + c4.x + c4.y;
  cursor[4 * t + 3] = excl + c4.x + c4.y + c4.z;
  cntf[4 * t + 0] = (float)c4.x;
  cntf[4 * t + 1] = (float)c4.y;
  cntf[4 * t + 2] = (float)c4.z;
  cntf[4 * t + 3] = (float)c4.w;
  if (t < 64) {
    float l = lpart[t];
    for (int m = 32; m; m >>= 1) l += __shfl_xor(l, m, 64);
    if (t == 0) out[0] = l * (1.f / (float)BATCH);
  }
}

// ============ place (blocks 0..63) + S chunks (blocks 64..127) ============
__global__ void k_place_S(const int* __restrict__ bmu, int* __restrict__ cursor,
                          int* __restrict__ perm,
                          const float* __restrict__ cntf, const float* __restrict__ Tf,
                          float* __restrict__ S) {
  int bid = blockIdx.x;
  int t = threadIdx.x;
  if (bid < 64) {
    int b = bid * 256 + t;
    int c = bmu[b];
    int p = atomicAdd(&cursor[c], 1);
    perm[p] = b;
  } else {
    int chunk = bid - 64;
    int cchunk = chunk >> 2;
    int kb = chunk & 3;
    int k = kb * 256 + t;
    float s = 0.f;
    for (int c = cchunk * 64; c < cchunk * 64 + 64; ++c)
      s += cntf[c] * Tf[(size_t)c * KNEUR + k];
    atomicAdd(&S[k], s);
  }
}

// ============ balanced class-segmented Xsum: Xf[c][i] (f32), 32/block ========
__global__ __launch_bounds__(256)
void k_xsum2(const int* __restrict__ perm, const int* __restrict__ bmu,
             const u16* __restrict__ xb, float* __restrict__ Xf) {
  int t = threadIdx.x;
  int m0 = blockIdx.x * 32;
  int pm[32], cl[32];
  #pragma unroll
  for (int j = 0; j < 32; ++j) pm[j] = perm[m0 + j];
  #pragma unroll
  for (int j = 0; j < 32; ++j) cl[j] = bmu[pm[j]];
  float a0 = 0.f, a1 = 0.f, a2 = 0.f, a3 = 0.f;
  int ccur = cl[0];
  #pragma unroll
  for (int j = 0; j < 32; ++j) {
    if (cl[j] != ccur) {
      float* p = Xf + (size_t)ccur * INDIM + 4 * t;
      atomicAdd(p + 0, a0); atomicAdd(p + 1, a1);
      atomicAdd(p + 2, a2); atomicAdd(p + 3, a3);
      a0 = a1 = a2 = a3 = 0.f;
      ccur = cl[j];
    }
    ushort4 v = *(const ushort4*)(xb + (size_t)pm[j] * INDIM + t * 4);
    a0 += bf2f(v.x); a1 += bf2f(v.y); a2 += bf2f(v.z); a3 += bf2f(v.w);
  }
  float* p = Xf + (size_t)ccur * INDIM + 4 * t;
  atomicAdd(p + 0, a0); atomicAdd(p + 1, a1);
  atomicAdd(p + 2, a2); atomicAdd(p + 3, a3);
}

// ============ Xf->xst transpose (0..255) + outw base write (256..511) ========
__global__ void k_trans_base(const float* __restrict__ Xf, u16* __restrict__ xst,
                             const float* __restrict__ w, const float* __restrict__ S,
                             float* __restrict__ outw) {
  int bid = blockIdx.x;
  int t = threadIdx.x;
  if (bid < 256) {
    __shared__ float tile[64][65];
    int bc = bid & 15;
    int bi = bid >> 4;
    int tx = t & 63, ty = t >> 6;
    int c0 = bc * 64, i0 = bi * 64;
    for (int r = ty; r < 64; r += 4)
      tile[r][tx] = Xf[(size_t)(c0 + r) * INDIM + i0 + tx];
    __syncthreads();
    for (int r = ty; r < 64; r += 4)
      xst[(size_t)(i0 + r) * KNEUR + c0 + tx] = f2bf(tile[tx][r]);
  } else {
    const float invB = 1.f / (float)BATCH;
    size_t base = ((size_t)(bid - 256) * 256 + t) * 16;
    int k = (int)(base & 1023);
    #pragma unroll
    for (int seg = 0; seg < 4; ++seg) {
      float4 wv = *(const float4*)(w + base + seg * 4);
      float4 sv = *(const float4*)(S + k + seg * 4);
      outw[base + seg * 4 + 0] = wv.x - wv.x * sv.x * invB;
      outw[base + seg * 4 + 1] = wv.y - wv.y * sv.y * invB;
      outw[base + seg * 4 + 2] = wv.z - wv.z * sv.z * invB;
      outw[base + seg * 4 + 3] = wv.w - wv.w * sv.w * invB;
    }
  }
}

// ============ reduce split-K partials into pre-based outw ============
__global__ void k_wupd(const float* __restrict__ P4, float* __restrict__ outw) {
  const float invB = 1.f / (float)BATCH;
  int id4 = blockIdx.x * 256 + threadIdx.x;
  size_t base = (size_t)id4 * 4;
  float4 p0 = *(const float4*)(P4 + base);
  float4 p1 = *(const float4*)(P4 + (1u << 20) + base);
  float4 p2 = *(const float4*)(P4 + (2u << 20) + base);
  float4 p3 = *(const float4*)(P4 + (3u << 20) + base);
  outw[base + 0] += (p0.x + p1.x + p2.x + p3.x) * invB;
  outw[base + 1] += (p0.y + p1.y + p2.y + p3.y) * invB;
  outw[base + 2] += (p0.z + p1.z + p2.z + p3.z) * invB;
  outw[base + 3] += (p0.w + p1.w + p2.w + p3.w) * invB;
}

extern "C" void kernel_launch(void* const* d_in, const int* in_sizes, int n_in,
                              void* d_out, int out_size, void* d_ws, size_t ws_size,
                              hipStream_t stream) {
  const float* x = (const float*)d_in[0];
  const float* w = (const float*)d_in[1];
  const int* loc = (const int*)d_in[2];
  const int* it = (const int*)d_in[3];
  float* out = (float*)d_out;

  char* ws = (char*)d_ws;
  size_t off = 0;
  auto alloc = [&](size_t bytes) -> void* {
    void* p = ws + off;
    off += (bytes + 255) & ~(size_t)255;
    return p;
  };
  u16* xb    = (u16*)  alloc((size_t)BATCH * INDIM * 2);     // 32 MB
  u16* wt    = (u16*)  alloc((size_t)KNEUR * INDIM * 2);
  u16* Tb    = (u16*)  alloc((size_t)KNEUR * KNEUR * 2);
  float* Tf  = (float*)alloc((size_t)KNEUR * KNEUR * 4);
  u16* xst   = (u16*)  alloc((size_t)INDIM * KNEUR * 2);
  float* x2  = (float*)alloc((size_t)BATCH * 4);
  float* w2  = (float*)alloc((size_t)KNEUR * 4);
  float* pmin= (float*)alloc((size_t)BATCH * 4 * 4);
  int* pidx  = (int*)  alloc((size_t)BATCH * 4 * 4);
  int* bmu   = (int*)  alloc((size_t)BATCH * 4);
  float* cntf= (float*)alloc((size_t)KNEUR * 4);
  float* S   = (float*)alloc((size_t)KNEUR * 4);
  float* lpart=(float*)alloc(64 * 4);
  float* Xf  = (float*)alloc((size_t)KNEUR * INDIM * 4);
  int* cntcur= (int*)  alloc((size_t)2304 * 4);   // cnt|cursor|ticket
  int* perm  = (int*)  alloc((size_t)BATCH * 4);
  if (off > ws_size) return;

  int* cnt = cntcur;
  int* cursor = cntcur + KNEUR;
  int* ticket = cntcur + 2 * KNEUR;
  float* outw = out + 1;
  float* P4 = (float*)xb;   // alias: xb dead after k_xsum2, before k_gemm2

  k_prep<<<8464, 256, 0, stream>>>(x, xb, x2, w, wt, w2, loc, it, Tb, Tf, Xf, cntcur, S);
  k_gemm1_8p<<<256, 512, 0, stream>>>(xb, wt, x2, w2, pmin, pidx);
  k_bmu_scan<<<64, 256, 0, stream>>>(pmin, pidx, bmu, lpart, cnt, ticket, cursor, cntf, out);
  k_place_S<<<128, 256, 0, stream>>>(bmu, cursor, perm, cntf, Tf, S);
  k_xsum2<<<BATCH / 32, 256, 0, stream>>>(perm, bmu, xb, Xf);
  k_trans_base<<<512, 256, 0, stream>>>(Xf, xst, w, S, outw);
  k_gemm2<<<256, 256, 0, stream>>>(xst, Tb, P4);
  k_wupd<<<1024, 256, 0, stream>>>(P4, outw);
}

// Round 10
// 144.730 us; speedup vs baseline: 1.0764x; 1.0580x over previous
//
#include <hip/hip_runtime.h>

typedef unsigned short u16;
typedef short bf16x8 __attribute__((ext_vector_type(8)));
typedef float f32x4 __attribute__((ext_vector_type(4)));

#define BATCH   16384
#define INDIM   1024
#define KNEUR   1024

__device__ __forceinline__ u16 f2bf(float f) {
  union { float f; unsigned u; } v; v.f = f;
  unsigned r = v.u + 0x7FFFu + ((v.u >> 16) & 1u);   // RNE
  return (u16)(r >> 16);
}
__device__ __forceinline__ float bf2f(u16 h) {
  union { unsigned u; float f; } v; v.u = ((unsigned)h) << 16; return v.f;
}

#define GLDS(gp, lp) __builtin_amdgcn_global_load_lds( \
  (const __attribute__((address_space(1))) void*)(gp), \
  (__attribute__((address_space(3))) void*)(lp), 16, 0, 0)

#define RAWBAR() __builtin_amdgcn_s_barrier()
#define LGKM0() do { asm volatile("s_waitcnt lgkmcnt(0)" ::: "memory"); \
                     __builtin_amdgcn_sched_barrier(0); } while (0)
#define LGKM8() asm volatile("s_waitcnt lgkmcnt(8)" ::: "memory")
#define VMC6() asm volatile("s_waitcnt vmcnt(6)" ::: "memory")
#define VMC0() asm volatile("s_waitcnt vmcnt(0)" ::: "memory")

// ============ PREP: x->bf16 + x2 | T table + zero-init | W^T | w2 ============
__global__ __launch_bounds__(256)
void k_prep(const float* __restrict__ x, u16* __restrict__ xb, float* __restrict__ x2,
            const float* __restrict__ w, u16* __restrict__ wt, float* __restrict__ w2,
            const int* __restrict__ loc, const int* __restrict__ itp,
            u16* __restrict__ Tb, float* __restrict__ Tf,
            float* __restrict__ Xf, int* __restrict__ cntcur, float* __restrict__ S) {
  __shared__ float tile[64][65];
  __shared__ float red[4][64];
  int bid = blockIdx.x;
  int t = threadIdx.x;
  if (bid < 4096) {
    int row = bid * 4 + (t >> 6);
    int l = t & 63;
    const float* xr = x + (size_t)row * INDIM;
    u16* xbr = xb + (size_t)row * INDIM;
    float s = 0.f;
    #pragma unroll
    for (int seg = 0; seg < 4; ++seg) {
      float4 v = *(const float4*)(xr + seg * 256 + l * 4);
      ushort4 o; o.x = f2bf(v.x); o.y = f2bf(v.y); o.z = f2bf(v.z); o.w = f2bf(v.w);
      *(ushort4*)(xbr + seg * 256 + l * 4) = o;
      s += v.x * v.x + v.y * v.y + v.z * v.z + v.w * v.w;
    }
    for (int m = 32; m; m >>= 1) s += __shfl_xor(s, m, 64);
    if (l == 0) x2[row] = s;
  } else if (bid < 8192) {
    int id = (bid - 4096) * 256 + t;     // c*1024 + k
    int c = id >> 10, k = id & 1023;
    float corr = 1.f - (float)itp[0] / 100.f;
    float lr = 0.3f * corr;
    float sig = 16.f * corr;
    float inv_s2 = 1.f / (sig * sig);
    int di = loc[2 * c] - loc[2 * k];
    int dj = loc[2 * c + 1] - loc[2 * k + 1];
    float v = lr * __expf(-(float)(di * di + dj * dj) * inv_s2);
    Tf[id] = v;
    Tb[id] = f2bf(v);
    Xf[id] = 0.f;
    if (id < 2304) cntcur[id] = 0;       // cnt[1024] + cursor[1024] + ticket + pad
    if (id < 1024) S[id] = 0.f;
  } else if (bid < 8448) {
    int bb = bid - 8192;
    int bi = bb & 15;
    int bj = bb >> 4;
    int tx = t & 63, ty = t >> 6;
    int i0 = bj * 64, k0 = bi * 64;
    for (int r = ty; r < 64; r += 4)
      tile[r][tx] = w[(size_t)(i0 + r) * KNEUR + k0 + tx];
    __syncthreads();
    for (int r = ty; r < 64; r += 4)
      wt[(size_t)(k0 + r) * INDIM + i0 + tx] = f2bf(tile[tx][r]);
  } else {
    int tx = t & 63, ty = t >> 6;
    int k = (bid - 8448) * 64 + tx;
    float s = 0.f;
    for (int i = ty * 256; i < ty * 256 + 256; ++i) {
      float v = w[(size_t)i * KNEUR + k];
      s += v * v;
    }
    red[ty][tx] = s;
    __syncthreads();
    if (ty == 0) w2[k] = red[0][tx] + red[1][tx] + red[2][tx] + red[3][tx];
  }
}

// ============ GEMM1: 256x256 8-phase MFMA + distance/argmin epilogue =========
// (frozen: round-7 proven version — 16x16x32 frags, XOR swizzle, vmcnt(6))
__global__ __launch_bounds__(512, 2)
void k_gemm1_8p(const u16* __restrict__ A, const u16* __restrict__ Bm,
                const float* __restrict__ x2, const float* __restrict__ w2,
                float* __restrict__ pmin, int* __restrict__ pidx) {
  __shared__ __align__(16) u16 lds[2][2][2][128 * 64];
  __shared__ float s_rv[2][256];
  __shared__ int   s_ri[2][256];

  int bid = blockIdx.x;
  int swz = (bid & 7) * 32 + (bid >> 3);   // XCD swizzle, 256 blocks
  int mb = swz >> 2, nb = swz & 3;
  int tid = threadIdx.x;
  int lane = tid & 63;
  int wm = (tid >> 6) >> 1, wn = (tid >> 6) & 1;

  const size_t rowA0 = (size_t)mb * 256;
  const size_t rowB0 = (size_t)nb * 256;

  auto STAGE = [&](int u, int op, int qh) {
    if (u >= 16) return;
    const u16* src = (op == 0) ? (A + (rowA0 + qh * 128) * 1024)
                               : (Bm + (rowB0 + qh * 128) * 1024);
    int k0 = u * 64;
    u16* dst0 = &lds[u & 1][op][qh][0];
    #pragma unroll
    for (int j = 0; j < 2; ++j) {
      int s = j * 512 + tid;
      int r = s >> 3;
      int cs = (s & 7) ^ (r & 7);            // inverse-swizzled global source
      GLDS(src + (size_t)r * 1024 + k0 + cs * 8, dst0 + (size_t)s * 8);
    }
  };
  auto LDA = [&](bf16x8 (&a)[2][2], int db, int qm) {
    #pragma unroll
    for (int mt = 0; mt < 2; ++mt)
      #pragma unroll
      for (int kk = 0; kk < 2; ++kk) {
        int row = wm * 32 + mt * 16 + (lane & 15);
        int ch = (kk * 4 + (lane >> 4)) ^ (row & 7);
        a[mt][kk] = *(const bf16x8*)(&lds[db][0][qm][row * 64 + ch * 8]);
      }
  };
  auto LDB = [&](bf16x8 (&b)[4][2], int db, int qn) {
    #pragma unroll
    for (int nt = 0; nt < 4; ++nt)
      #pragma unroll
      for (int kk = 0; kk < 2; ++kk) {
        int row = wn * 64 + nt * 16 + (lane & 15);
        int ch = (kk * 4 + (lane >> 4)) ^ (row & 7);
        b[nt][kk] = *(const bf16x8*)(&lds[db][1][qn][row * 64 + ch * 8]);
      }
  };

  f32x4 acc[2][2][2][4];   // [qm][qn][mt][nt]
  #pragma unroll
  for (int i = 0; i < 2; ++i)
    #pragma unroll
    for (int j = 0; j < 2; ++j)
      #pragma unroll
      for (int m = 0; m < 2; ++m)
        #pragma unroll
        for (int n = 0; n < 4; ++n) {
          acc[i][j][m][n][0] = 0.f; acc[i][j][m][n][1] = 0.f;
          acc[i][j][m][n][2] = 0.f; acc[i][j][m][n][3] = 0.f;
        }

  bf16x8 a[2][2], b0[4][2], b1[4][2];

  #define PHASE(accq, av, bv) do { \
    __builtin_amdgcn_s_setprio(1); \
    _Pragma("unroll") \
    for (int mt = 0; mt < 2; ++mt) \
      _Pragma("unroll") \
      for (int nt = 0; nt < 4; ++nt) \
        _Pragma("unroll") \
        for (int kk = 0; kk < 2; ++kk) \
          accq[mt][nt] = __builtin_amdgcn_mfma_f32_16x16x32_bf16(av[mt][kk], bv[nt][kk], accq[mt][nt], 0, 0, 0); \
    __builtin_amdgcn_s_setprio(0); \
  } while (0)

  // prologue: T0 all 4 halves, then T1 first 3 (order A0,B1,A1,B0)
  STAGE(0, 0, 0); STAGE(0, 1, 1); STAGE(0, 0, 1); STAGE(0, 1, 0);
  STAGE(1, 0, 0); STAGE(1, 1, 1); STAGE(1, 0, 1);
  VMC6();
  RAWBAR();

  for (int t = 0; t < 16; ++t) {
    int db = t & 1;
    // P0: quadrant (0,0) — 12 ds_reads, throttle with lgkmcnt(8)
    LDA(a, db, 0); LDB(b0, db, 0);
    STAGE(t + 1, 1, 0);                 // T(t+1).B0
    LGKM8();
    RAWBAR(); LGKM0();
    PHASE(acc[0][0], a, b0);
    RAWBAR();
    // P1: quadrant (0,1)
    LDB(b1, db, 1);
    STAGE(t + 2, 0, 0);                 // T(t+2).A0
    RAWBAR(); LGKM0();
    PHASE(acc[0][1], a, b1);
    RAWBAR();
    // P2: quadrant (1,1)
    LDA(a, db, 1);
    STAGE(t + 2, 1, 1);                 // T(t+2).B1
    RAWBAR(); LGKM0();
    PHASE(acc[1][1], a, b1);
    RAWBAR();
    // P3: quadrant (1,0)  (b0 reused from registers)
    STAGE(t + 2, 0, 1);                 // T(t+2).A1
    RAWBAR(); LGKM0();
    PHASE(acc[1][0], a, b0);
    if (t < 14) { VMC6(); } else { VMC0(); }
    RAWBAR();
  }

  // epilogue: d2 + min/argmin
  int g = lane >> 4, li = lane & 15;
  #pragma unroll
  for (int qm = 0; qm < 2; ++qm)
    #pragma unroll
    for (int mt = 0; mt < 2; ++mt)
      #pragma unroll
      for (int rr = 0; rr < 4; ++rr) {
        int lrow = qm * 128 + wm * 32 + mt * 16 + g * 4 + rr;
        float xv = x2[rowA0 + lrow];
        float v = 1e30f; int vi = 0x7fffffff;
        #pragma unroll
        for (int qn = 0; qn < 2; ++qn)
          #pragma unroll
          for (int nt = 0; nt < 4; ++nt) {
            int col = (int)rowB0 + qn * 128 + wn * 64 + nt * 16 + li;
            float d2 = xv + w2[col] - 2.f * acc[qm][qn][mt][nt][rr];
            if (d2 < v) { v = d2; vi = col; }
          }
        #pragma unroll
        for (int m = 1; m < 16; m <<= 1) {
          float ov = __shfl_xor(v, m, 64);
          int oi = __shfl_xor(vi, m, 64);
          if (ov < v || (ov == v && oi < vi)) { v = ov; vi = oi; }
        }
        if (li == 0) { s_rv[wn][lrow] = v; s_ri[wn][lrow] = vi; }
      }
  __syncthreads();
  if (tid < 256) {
    float v0 = s_rv[0][tid], v1 = s_rv[1][tid];
    int i0 = s_ri[0][tid], i1 = s_ri[1][tid];
    float v = v0; int vi = i0;
    if (v1 < v0 || (v1 == v0 && i1 < i0)) { v = v1; vi = i1; }
    size_t brow = rowA0 + tid;
    pmin[brow * 4 + nb] = v;
    pidx[brow * 4 + nb] = vi;
  }
  #undef PHASE
}

// ============ GEMM2 (m97 128^2 structure), split-K=8 partials into P8 ========
__global__ __launch_bounds__(256, 4)
void k_gemm2(const u16* __restrict__ A, const u16* __restrict__ Bm,
             float* __restrict__ P8) {
  __shared__ __align__(16) u16 ldsA[128 * 64];
  __shared__ __align__(16) u16 ldsB[128 * 64];

  int bid = blockIdx.x;
  int ks = bid & 7;
  int tile = bid >> 3;
  int mb = tile >> 3, nb = tile & 7;
  int ktlo = ks * 2, kthi = ktlo + 2;
  int lane = threadIdx.x & 63;
  int wid = threadIdx.x >> 6;
  int wr = wid >> 1, wc = wid & 1;

  f32x4 acc[4][4];
  #pragma unroll
  for (int i = 0; i < 4; ++i)
    #pragma unroll
    for (int j = 0; j < 4; ++j) { acc[i][j][0] = 0.f; acc[i][j][1] = 0.f; acc[i][j][2] = 0.f; acc[i][j][3] = 0.f; }

  const size_t rowA0 = (size_t)mb * 128;
  const size_t rowB0 = (size_t)nb * 128;

  for (int kt = ktlo; kt < kthi; ++kt) {
    int k0 = kt * 64;
    __syncthreads();
    #pragma unroll
    for (int q = 0; q < 4; ++q) {
      int p = q * 256 + wid * 64 + lane;
      int row = p >> 3;
      int clog = (p & 7) ^ (row & 7);
      GLDS(A + (rowA0 + row) * 1024 + k0 + clog * 8,
           ldsA + (size_t)(q * 256 + wid * 64) * 8);
    }
    #pragma unroll
    for (int q = 0; q < 4; ++q) {
      int p = q * 256 + wid * 64 + lane;
      int row = p >> 3;
      int clog = (p & 7) ^ (row & 7);
      GLDS(Bm + (rowB0 + row) * 1024 + k0 + clog * 8,
           ldsB + (size_t)(q * 256 + wid * 64) * 8);
    }
    __syncthreads();
    #pragma unroll
    for (int kk = 0; kk < 2; ++kk) {
      bf16x8 af[4], bfr[4];
      #pragma unroll
      for (int mt = 0; mt < 4; ++mt) {
        int row = wr * 64 + mt * 16 + (lane & 15);
        int ch = (kk * 4 + (lane >> 4)) ^ (row & 7);
        af[mt] = *(const bf16x8*)(ldsA + row * 64 + ch * 8);
      }
      #pragma unroll
      for (int nt = 0; nt < 4; ++nt) {
        int row = wc * 64 + nt * 16 + (lane & 15);
        int ch = (kk * 4 + (lane >> 4)) ^ (row & 7);
        bfr[nt] = *(const bf16x8*)(ldsB + row * 64 + ch * 8);
      }
      #pragma unroll
      for (int mt = 0; mt < 4; ++mt)
        #pragma unroll
        for (int nt = 0; nt < 4; ++nt)
          acc[mt][nt] = __builtin_amdgcn_mfma_f32_16x16x32_bf16(af[mt], bfr[nt], acc[mt][nt], 0, 0, 0);
    }
  }

  float* base = P8 + ((size_t)ks << 20);
  #pragma unroll
  for (int mt = 0; mt < 4; ++mt)
    #pragma unroll
    for (int nt = 0; nt < 4; ++nt)
      #pragma unroll
      for (int r = 0; r < 4; ++r) {
        int i = (int)rowA0 + wr * 64 + mt * 16 + (lane >> 4) * 4 + r;
        int k = (int)rowB0 + wc * 64 + nt * 16 + (lane & 15);
        base[(size_t)i * KNEUR + k] = acc[mt][nt][r];
      }
}

// ============ BMU + histogram + loss partials + last-block scan/loss ==========
__global__ void k_bmu_scan(const float* __restrict__ pmin, const int* __restrict__ pidx,
                           int* __restrict__ bmu, float* __restrict__ lpart,
                           int* __restrict__ cnt, int* __restrict__ ticket,
                           int* __restrict__ cursor, float* __restrict__ cntf,
                           float* __restrict__ out) {
  int t = threadIdx.x;
  int b = blockIdx.x * 256 + t;
  float v = 1e30f; int vi = 0;
  #pragma unroll
  for (int j = 0; j < 4; ++j) {
    float pv = pmin[(size_t)b * 4 + j];
    if (pv < v) { v = pv; vi = pidx[(size_t)b * 4 + j]; }
  }
  bmu[b] = vi;
  atomicAdd(&cnt[vi], 1);
  float d = sqrtf(fmaxf(v, 0.f));
  __shared__ float red[256];
  red[t] = d;
  __syncthreads();
  for (int s = 128; s > 0; s >>= 1) {
    if (t < s) red[t] += red[t + s];
    __syncthreads();
  }
  if (t == 0) lpart[blockIdx.x] = red[0];

  // last-block ticket: the 64th block to finish does the scan + loss
  __threadfence();
  __shared__ int is_last;
  if (t == 0) is_last = (atomicAdd(ticket, 1) == 63);
  __syncthreads();
  if (!is_last) return;

  __shared__ int sc[256];
  int4 c4 = *(const int4*)(cnt + 4 * t);
  int tsum = c4.x + c4.y + c4.z + c4.w;
  sc[t] = tsum;
  __syncthreads();
  for (int off = 1; off < 256; off <<= 1) {
    int val = sc[t];
    int add = (t >= off) ? sc[t - off] : 0;
    __syncthreads();
    sc[t] = val + add;
    __syncthreads();
  }
  int excl = sc[t] - tsum;
  cursor[4 * t + 0] = excl;
  cursor[4 * t + 1] = excl + c4.x;
  cursor[4 * t + 2] = excl + c4.x + c4.y;
  cursor[4 * t + 3] = excl + c4.x + c4.y + c4.z;
  cntf[4 * t + 0] = (float)c4.x;
  cntf[4 * t + 1] = (float)c4.y;
  cntf[4 * t + 2] = (float)c4.z;
  cntf[4 * t + 3] = (float)c4.w;
  if (t < 64) {
    float l = lpart[t];
    for (int m = 32; m; m >>= 1) l += __shfl_xor(l, m, 64);
    if (t == 0) out[0] = l * (1.f / (float)BATCH);
  }
}

// ============ place (blocks 0..63) + S chunks (blocks 64..127) ============
__global__ void k_place_S(const int* __restrict__ bmu, int* __restrict__ cursor,
                          int* __restrict__ perm,
                          const float* __restrict__ cntf, const float* __restrict__ Tf,
                          float* __restrict__ S) {
  int bid = blockIdx.x;
  int t = threadIdx.x;
  if (bid < 64) {
    int b = bid * 256 + t;
    int c = bmu[b];
    int p = atomicAdd(&cursor[c], 1);
    perm[p] = b;
  } else {
    int chunk = bid - 64;
    int cchunk = chunk >> 2;
    int kb = chunk & 3;
    int k = kb * 256 + t;
    float s = 0.f;
    for (int c = cchunk * 64; c < cchunk * 64 + 64; ++c)
      s += cntf[c] * Tf[(size_t)c * KNEUR + k];
    atomicAdd(&S[k], s);
  }
}

// ============ balanced class-segmented Xsum: Xf[c][i] (f32), 32/block ========
__global__ __launch_bounds__(256)
void k_xsum2(const int* __restrict__ perm, const int* __restrict__ bmu,
             const u16* __restrict__ xb, float* __restrict__ Xf) {
  int t = threadIdx.x;
  int m0 = blockIdx.x * 32;
  int pm[32], cl[32];
  #pragma unroll
  for (int j = 0; j < 32; ++j) pm[j] = perm[m0 + j];
  #pragma unroll
  for (int j = 0; j < 32; ++j) cl[j] = bmu[pm[j]];
  float a0 = 0.f, a1 = 0.f, a2 = 0.f, a3 = 0.f;
  int ccur = cl[0];
  #pragma unroll
  for (int j = 0; j < 32; ++j) {
    if (cl[j] != ccur) {
      float* p = Xf + (size_t)ccur * INDIM + 4 * t;
      atomicAdd(p + 0, a0); atomicAdd(p + 1, a1);
      atomicAdd(p + 2, a2); atomicAdd(p + 3, a3);
      a0 = a1 = a2 = a3 = 0.f;
      ccur = cl[j];
    }
    ushort4 v = *(const ushort4*)(xb + (size_t)pm[j] * INDIM + t * 4);
    a0 += bf2f(v.x); a1 += bf2f(v.y); a2 += bf2f(v.z); a3 += bf2f(v.w);
  }
  float* p = Xf + (size_t)ccur * INDIM + 4 * t;
  atomicAdd(p + 0, a0); atomicAdd(p + 1, a1);
  atomicAdd(p + 2, a2); atomicAdd(p + 3, a3);
}

// ============ Xf->xst transpose (256 blocks) ============
__global__ void k_trans(const float* __restrict__ Xf, u16* __restrict__ xst) {
  int bid = blockIdx.x;
  int t = threadIdx.x;
  __shared__ float tile[64][65];
  int bc = bid & 15;
  int bi = bid >> 4;
  int tx = t & 63, ty = t >> 6;
  int c0 = bc * 64, i0 = bi * 64;
  for (int r = ty; r < 64; r += 4)
    tile[r][tx] = Xf[(size_t)(c0 + r) * INDIM + i0 + tx];
  __syncthreads();
  for (int r = ty; r < 64; r += 4)
    xst[(size_t)(i0 + r) * KNEUR + c0 + tx] = f2bf(tile[tx][r]);
}

// ============ reduce split-K partials + base + weight update ============
__global__ void k_wupd(const float* __restrict__ P8, const float* __restrict__ w,
                       const float* __restrict__ S, float* __restrict__ outw) {
  const float invB = 1.f / (float)BATCH;
  int id4 = blockIdx.x * 256 + threadIdx.x;   // 1M/4 threads
  size_t base = (size_t)id4 * 4;
  int k = (int)(base & 1023);
  float4 s0 = *(const float4*)(P8 + base);
  #pragma unroll
  for (int j = 1; j < 8; ++j) {
    float4 pj = *(const float4*)(P8 + ((size_t)j << 20) + base);
    s0.x += pj.x; s0.y += pj.y; s0.z += pj.z; s0.w += pj.w;
  }
  float4 wv = *(const float4*)(w + base);
  float4 sv = *(const float4*)(S + k);
  outw[base + 0] = wv.x + (s0.x - wv.x * sv.x) * invB;
  outw[base + 1] = wv.y + (s0.y - wv.y * sv.y) * invB;
  outw[base + 2] = wv.z + (s0.z - wv.z * sv.z) * invB;
  outw[base + 3] = wv.w + (s0.w - wv.w * sv.w) * invB;
}

extern "C" void kernel_launch(void* const* d_in, const int* in_sizes, int n_in,
                              void* d_out, int out_size, void* d_ws, size_t ws_size,
                              hipStream_t stream) {
  const float* x = (const float*)d_in[0];
  const float* w = (const float*)d_in[1];
  const int* loc = (const int*)d_in[2];
  const int* it = (const int*)d_in[3];
  float* out = (float*)d_out;

  char* ws = (char*)d_ws;
  size_t off = 0;
  auto alloc = [&](size_t bytes) -> void* {
    void* p = ws + off;
    off += (bytes + 255) & ~(size_t)255;
    return p;
  };
  u16* xb    = (u16*)  alloc((size_t)BATCH * INDIM * 2);     // 32 MB
  u16* wt    = (u16*)  alloc((size_t)KNEUR * INDIM * 2);
  u16* Tb    = (u16*)  alloc((size_t)KNEUR * KNEUR * 2);
  float* Tf  = (float*)alloc((size_t)KNEUR * KNEUR * 4);
  u16* xst   = (u16*)  alloc((size_t)INDIM * KNEUR * 2);
  float* x2  = (float*)alloc((size_t)BATCH * 4);
  float* w2  = (float*)alloc((size_t)KNEUR * 4);
  float* pmin= (float*)alloc((size_t)BATCH * 4 * 4);
  int* pidx  = (int*)  alloc((size_t)BATCH * 4 * 4);
  int* bmu   = (int*)  alloc((size_t)BATCH * 4);
  float* cntf= (float*)alloc((size_t)KNEUR * 4);
  float* S   = (float*)alloc((size_t)KNEUR * 4);
  float* lpart=(float*)alloc(64 * 4);
  float* Xf  = (float*)alloc((size_t)KNEUR * INDIM * 4);
  int* cntcur= (int*)  alloc((size_t)2304 * 4);   // cnt|cursor|ticket
  int* perm  = (int*)  alloc((size_t)BATCH * 4);
  if (off > ws_size) return;

  int* cnt = cntcur;
  int* cursor = cntcur + KNEUR;
  int* ticket = cntcur + 2 * KNEUR;
  float* outw = out + 1;
  float* P8 = (float*)xb;   // alias: xb dead after k_xsum2, before k_gemm2 (32 MB = 8 x 4 MB)

  k_prep<<<8464, 256, 0, stream>>>(x, xb, x2, w, wt, w2, loc, it, Tb, Tf, Xf, cntcur, S);
  k_gemm1_8p<<<256, 512, 0, stream>>>(xb, wt, x2, w2, pmin, pidx);
  k_bmu_scan<<<64, 256, 0, stream>>>(pmin, pidx, bmu, lpart, cnt, ticket, cursor, cntf, out);
  k_place_S<<<128, 256, 0, stream>>>(bmu, cursor, perm, cntf, Tf, S);
  k_xsum2<<<BATCH / 32, 256, 0, stream>>>(perm, bmu, xb, Xf);
  k_trans<<<256, 256, 0, stream>>>(Xf, xst);
  k_gemm2<<<512, 256, 0, stream>>>(xst, Tb, P8);
  k_wupd<<<1024, 256, 0, stream>>>(P8, w, S, outw);
}

// Round 11
// 134.990 us; speedup vs baseline: 1.1540x; 1.0722x over previous
//
#include <hip/hip_runtime.h>

typedef unsigned short u16;
typedef short bf16x8 __attribute__((ext_vector_type(8)));
typedef float f32x4 __attribute__((ext_vector_type(4)));

#define BATCH   16384
#define INDIM   1024
#define KNEUR   1024

__device__ __forceinline__ u16 f2bf(float f) {
  union { float f; unsigned u; } v; v.f = f;
  unsigned r = v.u + 0x7FFFu + ((v.u >> 16) & 1u);   // RNE
  return (u16)(r >> 16);
}
__device__ __forceinline__ float bf2f(u16 h) {
  union { unsigned u; float f; } v; v.u = ((unsigned)h) << 16; return v.f;
}

#define GLDS(gp, lp) __builtin_amdgcn_global_load_lds( \
  (const __attribute__((address_space(1))) void*)(gp), \
  (__attribute__((address_space(3))) void*)(lp), 16, 0, 0)

#define RAWBAR() __builtin_amdgcn_s_barrier()
#define LGKM0() do { asm volatile("s_waitcnt lgkmcnt(0)" ::: "memory"); \
                     __builtin_amdgcn_sched_barrier(0); } while (0)
#define LGKM8() asm volatile("s_waitcnt lgkmcnt(8)" ::: "memory")
#define VMC6() asm volatile("s_waitcnt vmcnt(6)" ::: "memory")
#define VMC0() asm volatile("s_waitcnt vmcnt(0)" ::: "memory")

// ============ PREP: x->bf16 + x2 | T table + zero-init | W^T | w2 ============
__global__ __launch_bounds__(256)
void k_prep(const float* __restrict__ x, u16* __restrict__ xb, float* __restrict__ x2,
            const float* __restrict__ w, u16* __restrict__ wt, float* __restrict__ w2,
            const int* __restrict__ loc, const int* __restrict__ itp,
            u16* __restrict__ Tb, float* __restrict__ Tf,
            float* __restrict__ Xf, int* __restrict__ cntcur, float* __restrict__ S) {
  __shared__ float tile[64][65];
  __shared__ float red[4][64];
  int bid = blockIdx.x;
  int t = threadIdx.x;
  if (bid < 4096) {
    int row = bid * 4 + (t >> 6);
    int l = t & 63;
    const float* xr = x + (size_t)row * INDIM;
    u16* xbr = xb + (size_t)row * INDIM;
    float s = 0.f;
    #pragma unroll
    for (int seg = 0; seg < 4; ++seg) {
      float4 v = *(const float4*)(xr + seg * 256 + l * 4);
      ushort4 o; o.x = f2bf(v.x); o.y = f2bf(v.y); o.z = f2bf(v.z); o.w = f2bf(v.w);
      *(ushort4*)(xbr + seg * 256 + l * 4) = o;
      s += v.x * v.x + v.y * v.y + v.z * v.z + v.w * v.w;
    }
    for (int m = 32; m; m >>= 1) s += __shfl_xor(s, m, 64);
    if (l == 0) x2[row] = s;
  } else if (bid < 8192) {
    int id = (bid - 4096) * 256 + t;     // c*1024 + k
    int c = id >> 10, k = id & 1023;
    float corr = 1.f - (float)itp[0] / 100.f;
    float lr = 0.3f * corr;
    float sig = 16.f * corr;
    float inv_s2 = 1.f / (sig * sig);
    int di = loc[2 * c] - loc[2 * k];
    int dj = loc[2 * c + 1] - loc[2 * k + 1];
    float v = lr * __expf(-(float)(di * di + dj * dj) * inv_s2);
    Tf[id] = v;
    Tb[id] = f2bf(v);
    Xf[id] = 0.f;
    if (id < 2304) cntcur[id] = 0;       // cnt[1024] + cursor[1024] + ticket + pad
    if (id < 1024) S[id] = 0.f;
  } else if (bid < 8448) {
    int bb = bid - 8192;
    int bi = bb & 15;
    int bj = bb >> 4;
    int tx = t & 63, ty = t >> 6;
    int i0 = bj * 64, k0 = bi * 64;
    for (int r = ty; r < 64; r += 4)
      tile[r][tx] = w[(size_t)(i0 + r) * KNEUR + k0 + tx];
    __syncthreads();
    for (int r = ty; r < 64; r += 4)
      wt[(size_t)(k0 + r) * INDIM + i0 + tx] = f2bf(tile[tx][r]);
  } else {
    int tx = t & 63, ty = t >> 6;
    int k = (bid - 8448) * 64 + tx;
    float s = 0.f;
    for (int i = ty * 256; i < ty * 256 + 256; ++i) {
      float v = w[(size_t)i * KNEUR + k];
      s += v * v;
    }
    red[ty][tx] = s;
    __syncthreads();
    if (ty == 0) w2[k] = red[0][tx] + red[1][tx] + red[2][tx] + red[3][tx];
  }
}

// ============ GEMM1: 256x256 8-phase MFMA + distance/argmin epilogue =========
// (frozen: round-7 proven version — 16x16x32 frags, XOR swizzle, vmcnt(6))
__global__ __launch_bounds__(512, 2)
void k_gemm1_8p(const u16* __restrict__ A, const u16* __restrict__ Bm,
                const float* __restrict__ x2, const float* __restrict__ w2,
                float* __restrict__ pmin, int* __restrict__ pidx) {
  __shared__ __align__(16) u16 lds[2][2][2][128 * 64];
  __shared__ float s_rv[2][256];
  __shared__ int   s_ri[2][256];

  int bid = blockIdx.x;
  int swz = (bid & 7) * 32 + (bid >> 3);   // XCD swizzle, 256 blocks
  int mb = swz >> 2, nb = swz & 3;
  int tid = threadIdx.x;
  int lane = tid & 63;
  int wm = (tid >> 6) >> 1, wn = (tid >> 6) & 1;

  const size_t rowA0 = (size_t)mb * 256;
  const size_t rowB0 = (size_t)nb * 256;

  auto STAGE = [&](int u, int op, int qh) {
    if (u >= 16) return;
    const u16* src = (op == 0) ? (A + (rowA0 + qh * 128) * 1024)
                               : (Bm + (rowB0 + qh * 128) * 1024);
    int k0 = u * 64;
    u16* dst0 = &lds[u & 1][op][qh][0];
    #pragma unroll
    for (int j = 0; j < 2; ++j) {
      int s = j * 512 + tid;
      int r = s >> 3;
      int cs = (s & 7) ^ (r & 7);            // inverse-swizzled global source
      GLDS(src + (size_t)r * 1024 + k0 + cs * 8, dst0 + (size_t)s * 8);
    }
  };
  auto LDA = [&](bf16x8 (&a)[2][2], int db, int qm) {
    #pragma unroll
    for (int mt = 0; mt < 2; ++mt)
      #pragma unroll
      for (int kk = 0; kk < 2; ++kk) {
        int row = wm * 32 + mt * 16 + (lane & 15);
        int ch = (kk * 4 + (lane >> 4)) ^ (row & 7);
        a[mt][kk] = *(const bf16x8*)(&lds[db][0][qm][row * 64 + ch * 8]);
      }
  };
  auto LDB = [&](bf16x8 (&b)[4][2], int db, int qn) {
    #pragma unroll
    for (int nt = 0; nt < 4; ++nt)
      #pragma unroll
      for (int kk = 0; kk < 2; ++kk) {
        int row = wn * 64 + nt * 16 + (lane & 15);
        int ch = (kk * 4 + (lane >> 4)) ^ (row & 7);
        b[nt][kk] = *(const bf16x8*)(&lds[db][1][qn][row * 64 + ch * 8]);
      }
  };

  f32x4 acc[2][2][2][4];   // [qm][qn][mt][nt]
  #pragma unroll
  for (int i = 0; i < 2; ++i)
    #pragma unroll
    for (int j = 0; j < 2; ++j)
      #pragma unroll
      for (int m = 0; m < 2; ++m)
        #pragma unroll
        for (int n = 0; n < 4; ++n) {
          acc[i][j][m][n][0] = 0.f; acc[i][j][m][n][1] = 0.f;
          acc[i][j][m][n][2] = 0.f; acc[i][j][m][n][3] = 0.f;
        }

  bf16x8 a[2][2], b0[4][2], b1[4][2];

  #define PHASE(accq, av, bv) do { \
    __builtin_amdgcn_s_setprio(1); \
    _Pragma("unroll") \
    for (int mt = 0; mt < 2; ++mt) \
      _Pragma("unroll") \
      for (int nt = 0; nt < 4; ++nt) \
        _Pragma("unroll") \
        for (int kk = 0; kk < 2; ++kk) \
          accq[mt][nt] = __builtin_amdgcn_mfma_f32_16x16x32_bf16(av[mt][kk], bv[nt][kk], accq[mt][nt], 0, 0, 0); \
    __builtin_amdgcn_s_setprio(0); \
  } while (0)

  // prologue: T0 all 4 halves, then T1 first 3 (order A0,B1,A1,B0)
  STAGE(0, 0, 0); STAGE(0, 1, 1); STAGE(0, 0, 1); STAGE(0, 1, 0);
  STAGE(1, 0, 0); STAGE(1, 1, 1); STAGE(1, 0, 1);
  VMC6();
  RAWBAR();

  for (int t = 0; t < 16; ++t) {
    int db = t & 1;
    // P0: quadrant (0,0) — 12 ds_reads, throttle with lgkmcnt(8)
    LDA(a, db, 0); LDB(b0, db, 0);
    STAGE(t + 1, 1, 0);                 // T(t+1).B0
    LGKM8();
    RAWBAR(); LGKM0();
    PHASE(acc[0][0], a, b0);
    RAWBAR();
    // P1: quadrant (0,1)
    LDB(b1, db, 1);
    STAGE(t + 2, 0, 0);                 // T(t+2).A0
    RAWBAR(); LGKM0();
    PHASE(acc[0][1], a, b1);
    RAWBAR();
    // P2: quadrant (1,1)
    LDA(a, db, 1);
    STAGE(t + 2, 1, 1);                 // T(t+2).B1
    RAWBAR(); LGKM0();
    PHASE(acc[1][1], a, b1);
    RAWBAR();
    // P3: quadrant (1,0)  (b0 reused from registers)
    STAGE(t + 2, 0, 1);                 // T(t+2).A1
    RAWBAR(); LGKM0();
    PHASE(acc[1][0], a, b0);
    if (t < 14) { VMC6(); } else { VMC0(); }
    RAWBAR();
  }

  // epilogue: d2 + min/argmin
  int g = lane >> 4, li = lane & 15;
  #pragma unroll
  for (int qm = 0; qm < 2; ++qm)
    #pragma unroll
    for (int mt = 0; mt < 2; ++mt)
      #pragma unroll
      for (int rr = 0; rr < 4; ++rr) {
        int lrow = qm * 128 + wm * 32 + mt * 16 + g * 4 + rr;
        float xv = x2[rowA0 + lrow];
        float v = 1e30f; int vi = 0x7fffffff;
        #pragma unroll
        for (int qn = 0; qn < 2; ++qn)
          #pragma unroll
          for (int nt = 0; nt < 4; ++nt) {
            int col = (int)rowB0 + qn * 128 + wn * 64 + nt * 16 + li;
            float d2 = xv + w2[col] - 2.f * acc[qm][qn][mt][nt][rr];
            if (d2 < v) { v = d2; vi = col; }
          }
        #pragma unroll
        for (int m = 1; m < 16; m <<= 1) {
          float ov = __shfl_xor(v, m, 64);
          int oi = __shfl_xor(vi, m, 64);
          if (ov < v || (ov == v && oi < vi)) { v = ov; vi = oi; }
        }
        if (li == 0) { s_rv[wn][lrow] = v; s_ri[wn][lrow] = vi; }
      }
  __syncthreads();
  if (tid < 256) {
    float v0 = s_rv[0][tid], v1 = s_rv[1][tid];
    int i0 = s_ri[0][tid], i1 = s_ri[1][tid];
    float v = v0; int vi = i0;
    if (v1 < v0 || (v1 == v0 && i1 < i0)) { v = v1; vi = i1; }
    size_t brow = rowA0 + tid;
    pmin[brow * 4 + nb] = v;
    pidx[brow * 4 + nb] = vi;
  }
  #undef PHASE
}

// ============ GEMM2f: full-K 64x64 tile, 2-phase dbuf, fused weight update ===
// 256 blocks (16x16 tiles) x 256 threads (4 waves, each 32x32 output).
// outw = w + (P - w*S[k]) / B  written directly — no partials, no extra pass.
__global__ __launch_bounds__(256, 2)
void k_gemm2f(const u16* __restrict__ A, const u16* __restrict__ Bm,
              const float* __restrict__ w, const float* __restrict__ S,
              float* __restrict__ outw) {
  __shared__ __align__(16) u16 ldsA[2][64 * 64];
  __shared__ __align__(16) u16 ldsB[2][64 * 64];

  int bid = blockIdx.x;
  int mb = bid >> 4, nb = bid & 15;
  int tid = threadIdx.x;
  int lane = tid & 63;
  int wid = tid >> 6;
  int wr = wid >> 1, wc = wid & 1;

  const size_t rowA0 = (size_t)mb * 64;
  const size_t rowB0 = (size_t)nb * 64;

  auto STAGE2 = [&](int u, int buf) {
    int k0 = u * 64;
    #pragma unroll
    for (int j = 0; j < 2; ++j) {
      int s = j * 256 + tid;          // 0..511 slots, r = row, 8 chunks/row
      int r = s >> 3;
      int cs = (s & 7) ^ (r & 7);     // inverse-swizzled global source
      GLDS(A + (rowA0 + r) * 1024 + k0 + cs * 8, &ldsA[buf][s * 8]);
      GLDS(Bm + (rowB0 + r) * 1024 + k0 + cs * 8, &ldsB[buf][s * 8]);
    }
  };

  f32x4 acc[2][2];
  #pragma unroll
  for (int i = 0; i < 2; ++i)
    #pragma unroll
    for (int j = 0; j < 2; ++j) { acc[i][j][0] = 0.f; acc[i][j][1] = 0.f; acc[i][j][2] = 0.f; acc[i][j][3] = 0.f; }

  STAGE2(0, 0);
  VMC0();
  RAWBAR();

  for (int t = 0; t < 16; ++t) {
    int buf = t & 1;
    if (t < 15) STAGE2(t + 1, buf ^ 1);
    bf16x8 af[2][2], bfr[2][2];
    #pragma unroll
    for (int mt = 0; mt < 2; ++mt)
      #pragma unroll
      for (int kk = 0; kk < 2; ++kk) {
        int row = wr * 32 + mt * 16 + (lane & 15);
        int ch = (kk * 4 + (lane >> 4)) ^ (row & 7);
        af[mt][kk] = *(const bf16x8*)(&ldsA[buf][row * 64 + ch * 8]);
      }
    #pragma unroll
    for (int nt = 0; nt < 2; ++nt)
      #pragma unroll
      for (int kk = 0; kk < 2; ++kk) {
        int row = wc * 32 + nt * 16 + (lane & 15);
        int ch = (kk * 4 + (lane >> 4)) ^ (row & 7);
        bfr[nt][kk] = *(const bf16x8*)(&ldsB[buf][row * 64 + ch * 8]);
      }
    LGKM0();
    __builtin_amdgcn_s_setprio(1);
    #pragma unroll
    for (int mt = 0; mt < 2; ++mt)
      #pragma unroll
      for (int nt = 0; nt < 2; ++nt)
        #pragma unroll
        for (int kk = 0; kk < 2; ++kk)
          acc[mt][nt] = __builtin_amdgcn_mfma_f32_16x16x32_bf16(af[mt][kk], bfr[nt][kk], acc[mt][nt], 0, 0, 0);
    __builtin_amdgcn_s_setprio(0);
    if (t < 15) { VMC0(); RAWBAR(); }
  }

  const float invB = 1.f / (float)BATCH;
  #pragma unroll
  for (int mt = 0; mt < 2; ++mt)
    #pragma unroll
    for (int nt = 0; nt < 2; ++nt)
      #pragma unroll
      for (int r = 0; r < 4; ++r) {
        int i = (int)rowA0 + wr * 32 + mt * 16 + (lane >> 4) * 4 + r;
        int k = (int)rowB0 + wc * 32 + nt * 16 + (lane & 15);
        float wv = w[(size_t)i * KNEUR + k];
        outw[(size_t)i * KNEUR + k] = wv + (acc[mt][nt][r] - wv * S[k]) * invB;
      }
}

// ============ BMU + histogram + loss partials + last-block scan/loss ==========
__global__ void k_bmu_scan(const float* __restrict__ pmin, const int* __restrict__ pidx,
                           int* __restrict__ bmu, float* __restrict__ lpart,
                           int* __restrict__ cnt, int* __restrict__ ticket,
                           int* __restrict__ cursor, float* __restrict__ cntf,
                           float* __restrict__ out) {
  int t = threadIdx.x;
  int b = blockIdx.x * 256 + t;
  float v = 1e30f; int vi = 0;
  #pragma unroll
  for (int j = 0; j < 4; ++j) {
    float pv = pmin[(size_t)b * 4 + j];
    if (pv < v) { v = pv; vi = pidx[(size_t)b * 4 + j]; }
  }
  bmu[b] = vi;
  atomicAdd(&cnt[vi], 1);
  float d = sqrtf(fmaxf(v, 0.f));
  __shared__ float red[256];
  red[t] = d;
  __syncthreads();
  for (int s = 128; s > 0; s >>= 1) {
    if (t < s) red[t] += red[t + s];
    __syncthreads();
  }
  if (t == 0) lpart[blockIdx.x] = red[0];

  // last-block ticket: the 64th block to finish does the scan + loss
  __threadfence();
  __shared__ int is_last;
  if (t == 0) is_last = (atomicAdd(ticket, 1) == 63);
  __syncthreads();
  if (!is_last) return;

  __shared__ int sc[256];
  int4 c4 = *(const int4*)(cnt + 4 * t);
  int tsum = c4.x + c4.y + c4.z + c4.w;
  sc[t] = tsum;
  __syncthreads();
  for (int off = 1; off < 256; off <<= 1) {
    int val = sc[t];
    int add = (t >= off) ? sc[t - off] : 0;
    __syncthreads();
    sc[t] = val + add;
    __syncthreads();
  }
  int excl = sc[t] - tsum;
  cursor[4 * t + 0] = excl;
  cursor[4 * t + 1] = excl + c4.x;
  cursor[4 * t + 2] = excl + c4.x + c4.y;
  cursor[4 * t + 3] = excl + c4.x + c4.y + c4.z;
  cntf[4 * t + 0] = (float)c4.x;
  cntf[4 * t + 1] = (float)c4.y;
  cntf[4 * t + 2] = (float)c4.z;
  cntf[4 * t + 3] = (float)c4.w;
  if (t < 64) {
    float l = lpart[t];
    for (int m = 32; m; m >>= 1) l += __shfl_xor(l, m, 64);
    if (t == 0) out[0] = l * (1.f / (float)BATCH);
  }
}

// ============ place (blocks 0..63) + S chunks (blocks 64..127) ============
__global__ void k_place_S(const int* __restrict__ bmu, int* __restrict__ cursor,
                          int* __restrict__ perm,
                          const float* __restrict__ cntf, const float* __restrict__ Tf,
                          float* __restrict__ S) {
  int bid = blockIdx.x;
  int t = threadIdx.x;
  if (bid < 64) {
    int b = bid * 256 + t;
    int c = bmu[b];
    int p = atomicAdd(&cursor[c], 1);
    perm[p] = b;
  } else {
    int chunk = bid - 64;
    int cchunk = chunk >> 2;
    int kb = chunk & 3;
    int k = kb * 256 + t;
    float s = 0.f;
    for (int c = cchunk * 64; c < cchunk * 64 + 64; ++c)
      s += cntf[c] * Tf[(size_t)c * KNEUR + k];
    atomicAdd(&S[k], s);
  }
}

// ============ balanced class-segmented Xsum: Xf[c][i] (f32), 32/block ========
__global__ __launch_bounds__(256)
void k_xsum2(const int* __restrict__ perm, const int* __restrict__ bmu,
             const u16* __restrict__ xb, float* __restrict__ Xf) {
  int t = threadIdx.x;
  int m0 = blockIdx.x * 32;
  int pm[32], cl[32];
  #pragma unroll
  for (int j = 0; j < 32; ++j) pm[j] = perm[m0 + j];
  #pragma unroll
  for (int j = 0; j < 32; ++j) cl[j] = bmu[pm[j]];
  float a0 = 0.f, a1 = 0.f, a2 = 0.f, a3 = 0.f;
  int ccur = cl[0];
  #pragma unroll
  for (int j = 0; j < 32; ++j) {
    if (cl[j] != ccur) {
      float* p = Xf + (size_t)ccur * INDIM + 4 * t;
      atomicAdd(p + 0, a0); atomicAdd(p + 1, a1);
      atomicAdd(p + 2, a2); atomicAdd(p + 3, a3);
      a0 = a1 = a2 = a3 = 0.f;
      ccur = cl[j];
    }
    ushort4 v = *(const ushort4*)(xb + (size_t)pm[j] * INDIM + t * 4);
    a0 += bf2f(v.x); a1 += bf2f(v.y); a2 += bf2f(v.z); a3 += bf2f(v.w);
  }
  float* p = Xf + (size_t)ccur * INDIM + 4 * t;
  atomicAdd(p + 0, a0); atomicAdd(p + 1, a1);
  atomicAdd(p + 2, a2); atomicAdd(p + 3, a3);
}

// ============ Xf->xst transpose (256 blocks) ============
__global__ void k_trans(const float* __restrict__ Xf, u16* __restrict__ xst) {
  int bid = blockIdx.x;
  int t = threadIdx.x;
  __shared__ float tile[64][65];
  int bc = bid & 15;
  int bi = bid >> 4;
  int tx = t & 63, ty = t >> 6;
  int c0 = bc * 64, i0 = bi * 64;
  for (int r = ty; r < 64; r += 4)
    tile[r][tx] = Xf[(size_t)(c0 + r) * INDIM + i0 + tx];
  __syncthreads();
  for (int r = ty; r < 64; r += 4)
    xst[(size_t)(i0 + r) * KNEUR + c0 + tx] = f2bf(tile[tx][r]);
}

extern "C" void kernel_launch(void* const* d_in, const int* in_sizes, int n_in,
                              void* d_out, int out_size, void* d_ws, size_t ws_size,
                              hipStream_t stream) {
  const float* x = (const float*)d_in[0];
  const float* w = (const float*)d_in[1];
  const int* loc = (const int*)d_in[2];
  const int* it = (const int*)d_in[3];
  float* out = (float*)d_out;

  char* ws = (char*)d_ws;
  size_t off = 0;
  auto alloc = [&](size_t bytes) -> void* {
    void* p = ws + off;
    off += (bytes + 255) & ~(size_t)255;
    return p;
  };
  u16* xb    = (u16*)  alloc((size_t)BATCH * INDIM * 2);     // 32 MB
  u16* wt    = (u16*)  alloc((size_t)KNEUR * INDIM * 2);
  u16* Tb    = (u16*)  alloc((size_t)KNEUR * KNEUR * 2);
  float* Tf  = (float*)alloc((size_t)KNEUR * KNEUR * 4);
  u16* xst   = (u16*)  alloc((size_t)INDIM * KNEUR * 2);
  float* x2  = (float*)alloc((size_t)BATCH * 4);
  float* w2  = (float*)alloc((size_t)KNEUR * 4);
  float* pmin= (float*)alloc((size_t)BATCH * 4 * 4);
  int* pidx  = (int*)  alloc((size_t)BATCH * 4 * 4);
  int* bmu   = (int*)  alloc((size_t)BATCH * 4);
  float* cntf= (float*)alloc((size_t)KNEUR * 4);
  float* S   = (float*)alloc((size_t)KNEUR * 4);
  float* lpart=(float*)alloc(64 * 4);
  float* Xf  = (float*)alloc((size_t)KNEUR * INDIM * 4);
  int* cntcur= (int*)  alloc((size_t)2304 * 4);   // cnt|cursor|ticket
  int* perm  = (int*)  alloc((size_t)BATCH * 4);
  if (off > ws_size) return;

  int* cnt = cntcur;
  int* cursor = cntcur + KNEUR;
  int* ticket = cntcur + 2 * KNEUR;
  float* outw = out + 1;

  k_prep<<<8464, 256, 0, stream>>>(x, xb, x2, w, wt, w2, loc, it, Tb, Tf, Xf, cntcur, S);
  k_gemm1_8p<<<256, 512, 0, stream>>>(xb, wt, x2, w2, pmin, pidx);
  k_bmu_scan<<<64, 256, 0, stream>>>(pmin, pidx, bmu, lpart, cnt, ticket, cursor, cntf, out);
  k_place_S<<<128, 256, 0, stream>>>(bmu, cursor, perm, cntf, Tf, S);
  k_xsum2<<<BATCH / 32, 256, 0, stream>>>(perm, bmu, xb, Xf);
  k_trans<<<256, 256, 0, stream>>>(Xf, xst);
  k_gemm2f<<<256, 256, 0, stream>>>(xst, Tb, w, S, outw);
}